// Round 1
// baseline (1631.114 us; speedup 1.0000x reference)
//
#include <hip/hip_runtime.h>

#define N_ANG   360
#define N_DET   357
#define FILT_LEN 713
#define N_COLS  (N_ANG * N_DET)      // 128520
#define N_PIXK  65536
#define NNZK    8388608
#define NB      4

// ---------------------------------------------------------------------------
// Stage 1: r = sin_fan * cos, then SAME conv (len 713) along detector axis.
// Filter covers the whole row, so F[b,a,d] = sum_j r[j] * filt[356 + j - d].
// One block per (b,a). Writes X in [col][b] layout so stage 2 gathers float4.
// ---------------------------------------------------------------------------
__global__ void filt_kernel(const float* __restrict__ sin_fan,
                            const float* __restrict__ cosv,
                            const float* __restrict__ filt,
                            float* __restrict__ X) {
    __shared__ float s_r[N_DET];
    __shared__ float s_f[FILT_LEN];
    const int blk = blockIdx.x;            // b*N_ANG + a
    const int b   = blk / N_ANG;
    const int a   = blk % N_ANG;
    const int tid = threadIdx.x;

    for (int i = tid; i < N_DET; i += blockDim.x)
        s_r[i] = sin_fan[(size_t)(b * N_ANG + a) * N_DET + i] * cosv[a * N_DET + i];
    for (int i = tid; i < FILT_LEN; i += blockDim.x)
        s_f[i] = filt[i];
    __syncthreads();

    for (int d = tid; d < N_DET; d += blockDim.x) {
        float acc = 0.f;
        const float* fp = &s_f[356 - d];   // fp[j] = filt[356 + j - d]
        #pragma unroll 7
        for (int j = 0; j < N_DET; ++j)
            acc = fmaf(s_r[j], fp[j], acc);
        X[(size_t)(a * N_DET + d) * NB + b] = acc;
    }
}

__global__ void zero_kernel(float* __restrict__ p, int n) {
    int i = blockIdx.x * blockDim.x + threadIdx.x;
    if (i < n) p[i] = 0.f;
}

// ---------------------------------------------------------------------------
// Stage 2: gathered scatter-add. acc layout = [b][pix] (matches out.T flat).
// ---------------------------------------------------------------------------
__global__ void scatter_kernel(const float*  __restrict__ A_vals,
                               const int*    __restrict__ A_rows,
                               const int*    __restrict__ A_cols,
                               const float4* __restrict__ X4,
                               float* __restrict__ acc) {
    const int stride = gridDim.x * blockDim.x;
    for (int i = blockIdx.x * blockDim.x + threadIdx.x; i < NNZK; i += stride) {
        const float v = A_vals[i];
        const int   c = A_cols[i];
        const int   r = A_rows[i];
        const float4 x = X4[c];
        atomicAdd(&acc[0 * N_PIXK + r], v * x.x);
        atomicAdd(&acc[1 * N_PIXK + r], v * x.y);
        atomicAdd(&acc[2 * N_PIXK + r], v * x.z);
        atomicAdd(&acc[3 * N_PIXK + r], v * x.w);
    }
}

// ---------------------------------------------------------------------------
// Stage 3: clip to [0,1] into d_out.
// ---------------------------------------------------------------------------
__global__ void clip_kernel(const float* __restrict__ acc,
                            float* __restrict__ out, int n) {
    int i = blockIdx.x * blockDim.x + threadIdx.x;
    if (i < n) {
        float v = acc[i];
        out[i] = fminf(fmaxf(v, 0.f), 1.f);
    }
}

extern "C" void kernel_launch(void* const* d_in, const int* in_sizes, int n_in,
                              void* d_out, int out_size, void* d_ws, size_t ws_size,
                              hipStream_t stream) {
    const float* sin_fan = (const float*)d_in[0];
    const float* cosv    = (const float*)d_in[1];
    const float* filt    = (const float*)d_in[2];
    const float* A_vals  = (const float*)d_in[3];
    const int*   A_rows  = (const int*)d_in[4];
    const int*   A_cols  = (const int*)d_in[5];
    float* out = (float*)d_out;

    // ws layout: acc (NB*N_PIXK floats = 1 MB), then X (N_COLS*NB floats ~2 MB)
    float* acc = (float*)d_ws;
    float* X   = acc + (size_t)NB * N_PIXK;   // 1 MB offset -> 16B aligned

    zero_kernel<<<(NB * N_PIXK + 255) / 256, 256, 0, stream>>>(acc, NB * N_PIXK);
    filt_kernel<<<NB * N_ANG, 256, 0, stream>>>(sin_fan, cosv, filt, X);
    scatter_kernel<<<2048, 256, 0, stream>>>(A_vals, A_rows, A_cols,
                                             (const float4*)X, acc);
    clip_kernel<<<(NB * N_PIXK + 255) / 256, 256, 0, stream>>>(acc, out, NB * N_PIXK);
}

// Round 2
// 1629.744 us; speedup vs baseline: 1.0008x; 1.0008x over previous
//
#include <hip/hip_runtime.h>

#define N_ANG   360
#define N_DET   357
#define FILT_LEN 713
#define N_COLS  (N_ANG * N_DET)      // 128520
#define N_PIXK  65536
#define NNZK    8388608
#define NB      4

// ---------------------------------------------------------------------------
// Stage 1: r = sin_fan * cos, then SAME conv (len 713) along detector axis.
// Filter covers the whole row, so F[b,a,d] = sum_j r[j] * filt[356 + j - d].
// One block per (b,a). Writes X in [col][b] layout so stage 2 gathers float4.
// ---------------------------------------------------------------------------
__global__ void filt_kernel(const float* __restrict__ sin_fan,
                            const float* __restrict__ cosv,
                            const float* __restrict__ filt,
                            float* __restrict__ X) {
    __shared__ float s_r[N_DET];
    __shared__ float s_f[FILT_LEN];
    const int blk = blockIdx.x;            // b*N_ANG + a
    const int b   = blk / N_ANG;
    const int a   = blk % N_ANG;
    const int tid = threadIdx.x;

    for (int i = tid; i < N_DET; i += blockDim.x)
        s_r[i] = sin_fan[(size_t)(b * N_ANG + a) * N_DET + i] * cosv[a * N_DET + i];
    for (int i = tid; i < FILT_LEN; i += blockDim.x)
        s_f[i] = filt[i];
    __syncthreads();

    for (int d = tid; d < N_DET; d += blockDim.x) {
        float acc = 0.f;
        const float* fp = &s_f[356 - d];   // fp[j] = filt[356 + j - d]
        #pragma unroll 7
        for (int j = 0; j < N_DET; ++j)
            acc = fmaf(s_r[j], fp[j], acc);
        X[(size_t)(a * N_DET + d) * NB + b] = acc;
    }
}

__global__ void zero_kernel(float* __restrict__ p, int n) {
    int i = blockIdx.x * blockDim.x + threadIdx.x;
    if (i < n) p[i] = 0.f;
}

// ---------------------------------------------------------------------------
// Stage 2: gathered scatter-add. acc layout = [b][pix] (matches out.T flat).
// unsafeAtomicAdd -> hardware global_atomic_add_f32 (fire-and-forget), NOT
// the CAS retry loop that plain atomicAdd(float*) compiles to without
// -munsafe-fp-atomics. That CAS loop was the 1590us / 1.07GB-write bottleneck.
// ---------------------------------------------------------------------------
__global__ void scatter_kernel(const float*  __restrict__ A_vals,
                               const int*    __restrict__ A_rows,
                               const int*    __restrict__ A_cols,
                               const float4* __restrict__ X4,
                               float* __restrict__ acc) {
    const int stride = gridDim.x * blockDim.x;
    for (int i = blockIdx.x * blockDim.x + threadIdx.x; i < NNZK; i += stride) {
        const float v = A_vals[i];
        const int   c = A_cols[i];
        const int   r = A_rows[i];
        const float4 x = X4[c];
        unsafeAtomicAdd(&acc[0 * N_PIXK + r], v * x.x);
        unsafeAtomicAdd(&acc[1 * N_PIXK + r], v * x.y);
        unsafeAtomicAdd(&acc[2 * N_PIXK + r], v * x.z);
        unsafeAtomicAdd(&acc[3 * N_PIXK + r], v * x.w);
    }
}

// ---------------------------------------------------------------------------
// Stage 3: clip to [0,1] into d_out.
// ---------------------------------------------------------------------------
__global__ void clip_kernel(const float* __restrict__ acc,
                            float* __restrict__ out, int n) {
    int i = blockIdx.x * blockDim.x + threadIdx.x;
    if (i < n) {
        float v = acc[i];
        out[i] = fminf(fmaxf(v, 0.f), 1.f);
    }
}

extern "C" void kernel_launch(void* const* d_in, const int* in_sizes, int n_in,
                              void* d_out, int out_size, void* d_ws, size_t ws_size,
                              hipStream_t stream) {
    const float* sin_fan = (const float*)d_in[0];
    const float* cosv    = (const float*)d_in[1];
    const float* filt    = (const float*)d_in[2];
    const float* A_vals  = (const float*)d_in[3];
    const int*   A_rows  = (const int*)d_in[4];
    const int*   A_cols  = (const int*)d_in[5];
    float* out = (float*)d_out;

    // ws layout: acc (NB*N_PIXK floats = 1 MB), then X (N_COLS*NB floats ~2 MB)
    float* acc = (float*)d_ws;
    float* X   = acc + (size_t)NB * N_PIXK;   // 1 MB offset -> 16B aligned

    zero_kernel<<<(NB * N_PIXK + 255) / 256, 256, 0, stream>>>(acc, NB * N_PIXK);
    filt_kernel<<<NB * N_ANG, 256, 0, stream>>>(sin_fan, cosv, filt, X);
    scatter_kernel<<<2048, 256, 0, stream>>>(A_vals, A_rows, A_cols,
                                             (const float4*)X, acc);
    clip_kernel<<<(NB * N_PIXK + 255) / 256, 256, 0, stream>>>(acc, out, NB * N_PIXK);
}

// Round 3
// 767.809 us; speedup vs baseline: 2.1244x; 2.1226x over previous
//
#include <hip/hip_runtime.h>
#include <stdint.h>

#define N_ANG   360
#define N_DET   357
#define FILT_LEN 713
#define N_COLS  (N_ANG * N_DET)      // 128520
#define N_PIXK  65536
#define NNZK    8388608
#define NB      4
#define NXCD    8
#define FP_SCALE 16777216.0f          // 2^24
#define FP_INV   (1.0 / 16777216.0)

// ---------------------------------------------------------------------------
// Stage 1: r = sin_fan * cos, then SAME conv (len 713) along detector axis.
// Filter covers the whole row, so F[b,a,d] = sum_j r[j] * filt[356 + j - d].
// Writes X in [col][b] layout so stage 2 gathers float4.
// ---------------------------------------------------------------------------
__global__ void filt_kernel(const float* __restrict__ sin_fan,
                            const float* __restrict__ cosv,
                            const float* __restrict__ filt,
                            float* __restrict__ X) {
    __shared__ float s_r[N_DET];
    __shared__ float s_f[FILT_LEN];
    const int blk = blockIdx.x;            // b*N_ANG + a
    const int b   = blk / N_ANG;
    const int a   = blk % N_ANG;
    const int tid = threadIdx.x;

    for (int i = tid; i < N_DET; i += blockDim.x)
        s_r[i] = sin_fan[(size_t)(b * N_ANG + a) * N_DET + i] * cosv[a * N_DET + i];
    for (int i = tid; i < FILT_LEN; i += blockDim.x)
        s_f[i] = filt[i];
    __syncthreads();

    for (int d = tid; d < N_DET; d += blockDim.x) {
        float acc = 0.f;
        const float* fp = &s_f[356 - d];   // fp[j] = filt[356 + j - d]
        #pragma unroll 7
        for (int j = 0; j < N_DET; ++j)
            acc = fmaf(s_r[j], fp[j], acc);
        X[(size_t)(a * N_DET + d) * NB + b] = acc;
    }
}

__global__ void zero_u64_kernel(unsigned long long* __restrict__ p, int n) {
    int i = blockIdx.x * blockDim.x + threadIdx.x;
    if (i < n) p[i] = 0ULL;
}

__device__ __forceinline__ unsigned get_xcc_id() {
    unsigned x;
    asm volatile("s_getreg_b32 %0, hwreg(HW_REG_XCC_ID, 0, 4)" : "=s"(x));
    return x & (NXCD - 1);
}

// ---------------------------------------------------------------------------
// Stage 2: scatter-add into per-XCD replicas with L2-local (workgroup-scope,
// no sc1) u64 integer atomics. 4 f32 channels are fixed-point (2^24) packed
// as 2 per u64: low half exact mod 2^32; carries pollute the high half by
// 1 LSB (2^-24) each -> bounded ~1e-5 error, far under the 6.3e-4 threshold.
// Only same-XCD blocks touch a replica, so XCD-L2 atomicity suffices;
// dispatch-end release flushes dirty L2 lines for the reduce kernel.
// ---------------------------------------------------------------------------
__global__ void scatter_kernel(const float*  __restrict__ A_vals,
                               const int*    __restrict__ A_rows,
                               const int*    __restrict__ A_cols,
                               const float4* __restrict__ X4,
                               unsigned long long* __restrict__ rep) {
    unsigned long long* myrep = rep + (size_t)get_xcc_id() * N_PIXK * 2;
    const int stride = gridDim.x * blockDim.x;
    for (int i = blockIdx.x * blockDim.x + threadIdx.x; i < NNZK; i += stride) {
        const float v = A_vals[i];
        const int   c = A_cols[i];
        const int   r = A_rows[i];
        const float4 x = X4[c];
        const int i0 = __float2int_rn(v * x.x * FP_SCALE);
        const int i1 = __float2int_rn(v * x.y * FP_SCALE);
        const int i2 = __float2int_rn(v * x.z * FP_SCALE);
        const int i3 = __float2int_rn(v * x.w * FP_SCALE);
        const unsigned long long w0 =
            ((unsigned long long)(unsigned)i1 << 32) + (unsigned long long)(unsigned)i0;
        const unsigned long long w1 =
            ((unsigned long long)(unsigned)i3 << 32) + (unsigned long long)(unsigned)i2;
        __hip_atomic_fetch_add(&myrep[(size_t)r * 2 + 0], w0,
                               __ATOMIC_RELAXED, __HIP_MEMORY_SCOPE_WORKGROUP);
        __hip_atomic_fetch_add(&myrep[(size_t)r * 2 + 1], w1,
                               __ATOMIC_RELAXED, __HIP_MEMORY_SCOPE_WORKGROUP);
    }
}

// ---------------------------------------------------------------------------
// Stage 3: sum the 8 replicas (u64 adds, carry-tolerant), decode fixed point,
// clip, write out[b][pix].
// ---------------------------------------------------------------------------
__global__ void reduce_clip_kernel(const unsigned long long* __restrict__ rep,
                                   float* __restrict__ out) {
    const int p = blockIdx.x * blockDim.x + threadIdx.x;
    if (p >= N_PIXK) return;
    unsigned long long s0 = 0, s1 = 0;
    #pragma unroll
    for (int x = 0; x < NXCD; ++x) {
        s0 += rep[((size_t)x * N_PIXK + p) * 2 + 0];
        s1 += rep[((size_t)x * N_PIXK + p) * 2 + 1];
    }
    const float c0 = (float)((double)(int)(unsigned)(s0 & 0xffffffffULL) * FP_INV);
    const float c1 = (float)((double)(int)(unsigned)(s0 >> 32)           * FP_INV);
    const float c2 = (float)((double)(int)(unsigned)(s1 & 0xffffffffULL) * FP_INV);
    const float c3 = (float)((double)(int)(unsigned)(s1 >> 32)           * FP_INV);
    out[0 * N_PIXK + p] = fminf(fmaxf(c0, 0.f), 1.f);
    out[1 * N_PIXK + p] = fminf(fmaxf(c1, 0.f), 1.f);
    out[2 * N_PIXK + p] = fminf(fmaxf(c2, 0.f), 1.f);
    out[3 * N_PIXK + p] = fminf(fmaxf(c3, 0.f), 1.f);
}

// ------------------------- fallback (old slow path) ------------------------
__global__ void zero_kernel(float* __restrict__ p, int n) {
    int i = blockIdx.x * blockDim.x + threadIdx.x;
    if (i < n) p[i] = 0.f;
}
__global__ void scatter_fallback(const float*  __restrict__ A_vals,
                                 const int*    __restrict__ A_rows,
                                 const int*    __restrict__ A_cols,
                                 const float4* __restrict__ X4,
                                 float* __restrict__ acc) {
    const int stride = gridDim.x * blockDim.x;
    for (int i = blockIdx.x * blockDim.x + threadIdx.x; i < NNZK; i += stride) {
        const float v = A_vals[i];
        const float4 x = X4[A_cols[i]];
        const int   r = A_rows[i];
        atomicAdd(&acc[0 * N_PIXK + r], v * x.x);
        atomicAdd(&acc[1 * N_PIXK + r], v * x.y);
        atomicAdd(&acc[2 * N_PIXK + r], v * x.z);
        atomicAdd(&acc[3 * N_PIXK + r], v * x.w);
    }
}
__global__ void clip_kernel(const float* __restrict__ acc,
                            float* __restrict__ out, int n) {
    int i = blockIdx.x * blockDim.x + threadIdx.x;
    if (i < n) out[i] = fminf(fmaxf(acc[i], 0.f), 1.f);
}

extern "C" void kernel_launch(void* const* d_in, const int* in_sizes, int n_in,
                              void* d_out, int out_size, void* d_ws, size_t ws_size,
                              hipStream_t stream) {
    const float* sin_fan = (const float*)d_in[0];
    const float* cosv    = (const float*)d_in[1];
    const float* filt    = (const float*)d_in[2];
    const float* A_vals  = (const float*)d_in[3];
    const int*   A_rows  = (const int*)d_in[4];
    const int*   A_cols  = (const int*)d_in[5];
    float* out = (float*)d_out;

    const size_t rep_bytes = (size_t)NXCD * N_PIXK * 2 * sizeof(unsigned long long); // 16 MB... actually 8 MB
    const size_t x_bytes   = (size_t)N_COLS * NB * sizeof(float);                    // ~2 MB

    if (ws_size >= rep_bytes + x_bytes) {
        unsigned long long* rep = (unsigned long long*)d_ws;
        float* X = (float*)((char*)d_ws + rep_bytes);

        const int nrep = NXCD * N_PIXK * 2;
        zero_u64_kernel<<<(nrep + 255) / 256, 256, 0, stream>>>(rep, nrep);
        filt_kernel<<<NB * N_ANG, 256, 0, stream>>>(sin_fan, cosv, filt, X);
        scatter_kernel<<<4096, 256, 0, stream>>>(A_vals, A_rows, A_cols,
                                                 (const float4*)X, rep);
        reduce_clip_kernel<<<(N_PIXK + 255) / 256, 256, 0, stream>>>(rep, out);
    } else {
        // fallback: fits in 3.1 MB ws
        float* acc = (float*)d_ws;
        float* X   = acc + (size_t)NB * N_PIXK;
        zero_kernel<<<(NB * N_PIXK + 255) / 256, 256, 0, stream>>>(acc, NB * N_PIXK);
        filt_kernel<<<NB * N_ANG, 256, 0, stream>>>(sin_fan, cosv, filt, X);
        scatter_fallback<<<2048, 256, 0, stream>>>(A_vals, A_rows, A_cols,
                                                   (const float4*)X, acc);
        clip_kernel<<<(NB * N_PIXK + 255) / 256, 256, 0, stream>>>(acc, out, NB * N_PIXK);
    }
}

// Round 4
// 305.477 us; speedup vs baseline: 5.3396x; 2.5135x over previous
//
#include <hip/hip_runtime.h>
#include <stdint.h>

#define N_ANG    360
#define N_DET    357
#define FILT_LEN 713
#define N_COLS   (N_ANG * N_DET)      // 128520 < 2^17
#define N_PIXK   65536
#define NNZK     8388608
#define NB       4

#define NPART    256
#define PART_SH  8                    // partition = row >> 8
#define PART_PIX 256                  // pixels per partition
#define CHUNK    8192                 // nnz per chunk/block in passes 1-2
#define NCHUNK   (NNZK / CHUNK)       // 1024, exact
#define P2_T     256
#define P2_PER_T (CHUNK / P2_T)       // 32

// ---------------------------------------------------------------------------
// Stage 1: r = sin_fan * cos, SAME conv len-713 along detector axis.
// Filter covers whole row: F[b,a,d] = sum_j r[j] * filt[356 + j - d].
// X written [col][b] so accum gathers one float4 per nnz.
// ---------------------------------------------------------------------------
__global__ void filt_kernel(const float* __restrict__ sin_fan,
                            const float* __restrict__ cosv,
                            const float* __restrict__ filt,
                            float* __restrict__ X) {
    __shared__ float s_r[N_DET];
    __shared__ float s_f[FILT_LEN];
    const int blk = blockIdx.x;            // b*N_ANG + a
    const int b   = blk / N_ANG;
    const int a   = blk % N_ANG;
    const int tid = threadIdx.x;

    for (int i = tid; i < N_DET; i += blockDim.x)
        s_r[i] = sin_fan[(size_t)(b * N_ANG + a) * N_DET + i] * cosv[a * N_DET + i];
    for (int i = tid; i < FILT_LEN; i += blockDim.x)
        s_f[i] = filt[i];
    __syncthreads();

    for (int d = tid; d < N_DET; d += blockDim.x) {
        float acc = 0.f;
        const float* fp = &s_f[356 - d];
        #pragma unroll 7
        for (int j = 0; j < N_DET; ++j)
            acc = fmaf(s_r[j], fp[j], acc);
        X[(size_t)(a * N_DET + d) * NB + b] = acc;
    }
}

// ---------------------------------------------------------------------------
// Pass 1: per-chunk partition histogram (LDS atomics only).
// counts layout: [chunk][part] (chunk-major) so the scan reads coalesced.
// ---------------------------------------------------------------------------
__global__ void hist_kernel(const int* __restrict__ A_rows,
                            unsigned* __restrict__ counts) {
    __shared__ unsigned h[NPART];
    const int chunk = blockIdx.x, tid = threadIdx.x;
    h[tid] = 0;
    __syncthreads();
    const int base = chunk * CHUNK;
    #pragma unroll
    for (int k = 0; k < P2_PER_T; ++k) {
        int row = A_rows[base + k * P2_T + tid];
        atomicAdd(&h[row >> PART_SH], 1u);
    }
    __syncthreads();
    counts[chunk * NPART + tid] = h[tid];
}

// ---------------------------------------------------------------------------
// Pass 1.5: thread p owns partition p. Sum over chunks -> exclusive base per
// partition -> rewrite counts[c][p] in place as global write offsets.
// ---------------------------------------------------------------------------
__global__ void scan_kernel(unsigned* __restrict__ counts,
                            unsigned* __restrict__ part_base) {
    const int tid = threadIdx.x;   // 256
    __shared__ unsigned tot[NPART];
    __shared__ unsigned base[NPART + 1];
    unsigned sum = 0;
    for (int c = 0; c < NCHUNK; ++c) sum += counts[c * NPART + tid];
    tot[tid] = sum;
    __syncthreads();
    if (tid == 0) {
        unsigned r = 0;
        for (int i = 0; i < NPART; ++i) { base[i] = r; r += tot[i]; }
        base[NPART] = r;
    }
    __syncthreads();
    part_base[tid] = base[tid];
    if (tid == 0) part_base[NPART] = base[NPART];
    unsigned run = base[tid];
    for (int c = 0; c < NCHUNK; ++c) {
        unsigned v = counts[c * NPART + tid];
        counts[c * NPART + tid] = run;
        run += v;
    }
}

// ---------------------------------------------------------------------------
// Pass 2: reorder each chunk by partition in LDS, then write packed 8B
// entries (val f32, row_local<<17 | col) out as contiguous per-partition runs.
// ---------------------------------------------------------------------------
__global__ void bin_kernel(const float* __restrict__ A_vals,
                           const int*   __restrict__ A_rows,
                           const int*   __restrict__ A_cols,
                           const unsigned* __restrict__ offsets,
                           uint2* __restrict__ bins) {
    __shared__ uint2 stage[CHUNK];            // 64 KB
    __shared__ unsigned char spart[CHUNK];    // 8 KB
    __shared__ unsigned h[NPART], loff[NPART], cnt[NPART], goff[NPART];
    const int chunk = blockIdx.x, tid = threadIdx.x;
    h[tid] = 0; cnt[tid] = 0;
    __syncthreads();

    const int base = chunk * CHUNK;
    int rows[P2_PER_T];
    #pragma unroll
    for (int k = 0; k < P2_PER_T; ++k) {
        rows[k] = A_rows[base + k * P2_T + tid];
        atomicAdd(&h[rows[k] >> PART_SH], 1u);
    }
    __syncthreads();
    if (tid == 0) {
        unsigned r = 0;
        for (int p = 0; p < NPART; ++p) { loff[p] = r; r += h[p]; }
    }
    __syncthreads();
    goff[tid] = offsets[chunk * NPART + tid];

    #pragma unroll
    for (int k = 0; k < P2_PER_T; ++k) {
        const int i = base + k * P2_T + tid;
        const int row = rows[k];
        const unsigned col = (unsigned)A_cols[i];
        const float v = A_vals[i];
        const int p = row >> PART_SH;
        const unsigned rank = atomicAdd(&cnt[p], 1u);
        const unsigned pos = loff[p] + rank;
        stage[pos] = make_uint2(__float_as_uint(v),
                                ((unsigned)(row & (PART_PIX - 1)) << 17) | col);
        spart[pos] = (unsigned char)p;
    }
    __syncthreads();

    #pragma unroll
    for (int k = 0; k < P2_PER_T; ++k) {
        const int i = k * P2_T + tid;
        const unsigned p = spart[i];
        const unsigned glob = goff[p] + (unsigned)i - loff[p];
        bins[glob] = stage[i];
    }
}

// ---------------------------------------------------------------------------
// Pass 3: one block per partition. Stream the bin coalesced, gather X4[col]
// (L2-resident), accumulate in 4 KB LDS via native ds float atomics, then
// write the clipped output slice directly. Zero global atomics.
// facc layout [ch][rl]: random rl -> ~2 lanes/bank, conflict-free.
// ---------------------------------------------------------------------------
__global__ void __launch_bounds__(1024)
accum_kernel(const uint2* __restrict__ bins,
             const unsigned* __restrict__ part_base,
             const float4* __restrict__ X4,
             float* __restrict__ out) {
    __shared__ float facc[NB][PART_PIX];
    const int p = blockIdx.x, tid = threadIdx.x;
    ((float*)facc)[tid] = 0.f;
    __syncthreads();

    const unsigned s = part_base[p], e = part_base[p + 1];
    for (unsigned i = s + tid; i < e; i += 1024) {
        const uint2 en = bins[i];
        const float v = __uint_as_float(en.x);
        const unsigned col = en.y & 0x1FFFFu;
        const unsigned rl  = en.y >> 17;
        const float4 x = X4[col];
        atomicAdd(&facc[0][rl], v * x.x);
        atomicAdd(&facc[1][rl], v * x.y);
        atomicAdd(&facc[2][rl], v * x.z);
        atomicAdd(&facc[3][rl], v * x.w);
    }
    __syncthreads();

    const int ch = tid >> 8, rl = tid & (PART_PIX - 1);
    const float r = facc[ch][rl];
    out[(size_t)ch * N_PIXK + p * PART_PIX + rl] = fminf(fmaxf(r, 0.f), 1.f);
}

// ------------------------- fallback (round-3 path) -------------------------
#define NXCD 8
#define FP_SCALE 16777216.0f
#define FP_INV   (1.0 / 16777216.0)
__global__ void zero_u64_kernel(unsigned long long* __restrict__ p, int n) {
    int i = blockIdx.x * blockDim.x + threadIdx.x;
    if (i < n) p[i] = 0ULL;
}
__device__ __forceinline__ unsigned get_xcc_id() {
    unsigned x;
    asm volatile("s_getreg_b32 %0, hwreg(HW_REG_XCC_ID, 0, 4)" : "=s"(x));
    return x & (NXCD - 1);
}
__global__ void scatter_kernel(const float*  __restrict__ A_vals,
                               const int*    __restrict__ A_rows,
                               const int*    __restrict__ A_cols,
                               const float4* __restrict__ X4,
                               unsigned long long* __restrict__ rep) {
    unsigned long long* myrep = rep + (size_t)get_xcc_id() * N_PIXK * 2;
    const int stride = gridDim.x * blockDim.x;
    for (int i = blockIdx.x * blockDim.x + threadIdx.x; i < NNZK; i += stride) {
        const float v = A_vals[i];
        const float4 x = X4[A_cols[i]];
        const int r = A_rows[i];
        const int i0 = __float2int_rn(v * x.x * FP_SCALE);
        const int i1 = __float2int_rn(v * x.y * FP_SCALE);
        const int i2 = __float2int_rn(v * x.z * FP_SCALE);
        const int i3 = __float2int_rn(v * x.w * FP_SCALE);
        const unsigned long long w0 =
            ((unsigned long long)(unsigned)i1 << 32) + (unsigned long long)(unsigned)i0;
        const unsigned long long w1 =
            ((unsigned long long)(unsigned)i3 << 32) + (unsigned long long)(unsigned)i2;
        __hip_atomic_fetch_add(&myrep[(size_t)r * 2 + 0], w0,
                               __ATOMIC_RELAXED, __HIP_MEMORY_SCOPE_WORKGROUP);
        __hip_atomic_fetch_add(&myrep[(size_t)r * 2 + 1], w1,
                               __ATOMIC_RELAXED, __HIP_MEMORY_SCOPE_WORKGROUP);
    }
}
__global__ void reduce_clip_kernel(const unsigned long long* __restrict__ rep,
                                   float* __restrict__ out) {
    const int p = blockIdx.x * blockDim.x + threadIdx.x;
    if (p >= N_PIXK) return;
    unsigned long long s0 = 0, s1 = 0;
    #pragma unroll
    for (int x = 0; x < NXCD; ++x) {
        s0 += rep[((size_t)x * N_PIXK + p) * 2 + 0];
        s1 += rep[((size_t)x * N_PIXK + p) * 2 + 1];
    }
    const float c0 = (float)((double)(int)(unsigned)(s0 & 0xffffffffULL) * FP_INV);
    const float c1 = (float)((double)(int)(unsigned)(s0 >> 32)           * FP_INV);
    const float c2 = (float)((double)(int)(unsigned)(s1 & 0xffffffffULL) * FP_INV);
    const float c3 = (float)((double)(int)(unsigned)(s1 >> 32)           * FP_INV);
    out[0 * N_PIXK + p] = fminf(fmaxf(c0, 0.f), 1.f);
    out[1 * N_PIXK + p] = fminf(fmaxf(c1, 0.f), 1.f);
    out[2 * N_PIXK + p] = fminf(fmaxf(c2, 0.f), 1.f);
    out[3 * N_PIXK + p] = fminf(fmaxf(c3, 0.f), 1.f);
}

extern "C" void kernel_launch(void* const* d_in, const int* in_sizes, int n_in,
                              void* d_out, int out_size, void* d_ws, size_t ws_size,
                              hipStream_t stream) {
    const float* sin_fan = (const float*)d_in[0];
    const float* cosv    = (const float*)d_in[1];
    const float* filt    = (const float*)d_in[2];
    const float* A_vals  = (const float*)d_in[3];
    const int*   A_rows  = (const int*)d_in[4];
    const int*   A_cols  = (const int*)d_in[5];
    float* out = (float*)d_out;

    // ws layout for sort path:
    //   [0, 2MB)          X           (N_COLS*4 floats = 2,056,320 B)
    //   [2MB, 3MB)        counts      (NCHUNK*NPART u32 = 1 MB)
    //   [3MB, 3MB+4K)     part_base   (257 u32)
    //   [3MB+4K, +64MB)   bins        (NNZK uint2 = 64 MB)
    const size_t MB = 1024 * 1024;
    const size_t need_sort = 3 * MB + 4096 + (size_t)NNZK * sizeof(uint2);

    if (ws_size >= need_sort) {
        float*    X      = (float*)d_ws;
        unsigned* counts = (unsigned*)((char*)d_ws + 2 * MB);
        unsigned* pbase  = (unsigned*)((char*)d_ws + 3 * MB);
        uint2*    bins   = (uint2*)((char*)d_ws + 3 * MB + 4096);

        filt_kernel<<<NB * N_ANG, 256, 0, stream>>>(sin_fan, cosv, filt, X);
        hist_kernel<<<NCHUNK, P2_T, 0, stream>>>(A_rows, counts);
        scan_kernel<<<1, NPART, 0, stream>>>(counts, pbase);
        bin_kernel<<<NCHUNK, P2_T, 0, stream>>>(A_vals, A_rows, A_cols, counts, bins);
        accum_kernel<<<NPART, 1024, 0, stream>>>(bins, pbase, (const float4*)X, out);
    } else {
        // fallback: per-XCD replica atomic path (needs ~10 MB)
        unsigned long long* rep = (unsigned long long*)d_ws;
        const size_t rep_bytes = (size_t)NXCD * N_PIXK * 2 * sizeof(unsigned long long);
        float* X = (float*)((char*)d_ws + rep_bytes);
        const int nrep = NXCD * N_PIXK * 2;
        zero_u64_kernel<<<(nrep + 255) / 256, 256, 0, stream>>>(rep, nrep);
        filt_kernel<<<NB * N_ANG, 256, 0, stream>>>(sin_fan, cosv, filt, X);
        scatter_kernel<<<4096, 256, 0, stream>>>(A_vals, A_rows, A_cols,
                                                 (const float4*)X, rep);
        reduce_clip_kernel<<<(N_PIXK + 255) / 256, 256, 0, stream>>>(rep, out);
    }
}

// Round 5
// 267.280 us; speedup vs baseline: 6.1026x; 1.1429x over previous
//
#include <hip/hip_runtime.h>
#include <stdint.h>

#define N_ANG    360
#define N_DET    357
#define FILT_LEN 713
#define N_COLS   (N_ANG * N_DET)      // 128520 < 2^17
#define N_PIXK   65536
#define NNZK     8388608
#define NB       4

#define NPART    256
#define PART_SH  8                    // partition = row >> 8
#define PART_PIX 256                  // pixels per partition
#define CHUNK    8192                 // nnz per chunk/block in passes 1-2
#define NCHUNK   (NNZK / CHUNK)       // 1024, exact
#define P2_T     256
#define P2_PER_T (CHUNK / P2_T)       // 32

// ---------------------------------------------------------------------------
// Stage 1: r = sin_fan * cos, SAME conv len-713 along detector axis.
// Filter covers whole row: F[b,a,d] = sum_j r[j] * filt[356 + j - d].
// X written [col][b] so accum gathers one float4 per nnz.
// ---------------------------------------------------------------------------
__global__ void filt_kernel(const float* __restrict__ sin_fan,
                            const float* __restrict__ cosv,
                            const float* __restrict__ filt,
                            float* __restrict__ X) {
    __shared__ float s_r[N_DET];
    __shared__ float s_f[FILT_LEN];
    const int blk = blockIdx.x;            // b*N_ANG + a
    const int b   = blk / N_ANG;
    const int a   = blk % N_ANG;
    const int tid = threadIdx.x;

    for (int i = tid; i < N_DET; i += blockDim.x)
        s_r[i] = sin_fan[(size_t)(b * N_ANG + a) * N_DET + i] * cosv[a * N_DET + i];
    for (int i = tid; i < FILT_LEN; i += blockDim.x)
        s_f[i] = filt[i];
    __syncthreads();

    for (int d = tid; d < N_DET; d += blockDim.x) {
        float acc = 0.f;
        const float* fp = &s_f[356 - d];
        #pragma unroll 7
        for (int j = 0; j < N_DET; ++j)
            acc = fmaf(s_r[j], fp[j], acc);
        X[(size_t)(a * N_DET + d) * NB + b] = acc;
    }
}

// ---------------------------------------------------------------------------
// Pass 1: per-chunk partition histogram (LDS int atomics, native).
// counts layout: [chunk][part].
// ---------------------------------------------------------------------------
__global__ void hist_kernel(const int* __restrict__ A_rows,
                            unsigned* __restrict__ counts) {
    __shared__ unsigned h[NPART];
    const int chunk = blockIdx.x, tid = threadIdx.x;
    h[tid] = 0;
    __syncthreads();
    const int base = chunk * CHUNK;
    #pragma unroll
    for (int k = 0; k < P2_PER_T; ++k) {
        int row = A_rows[base + k * P2_T + tid];
        atomicAdd(&h[row >> PART_SH], 1u);
    }
    __syncthreads();
    counts[chunk * NPART + tid] = h[tid];
}

// ---------------------------------------------------------------------------
// Pass 1.5a: per-partition exclusive prefix over the 1024 chunks.
// Block p owns partition p; thread t owns chunks [4t, 4t+4).
// Rewrites counts[c][p] to the within-partition offset; ptot[p] = total.
// ---------------------------------------------------------------------------
__global__ void scanA_kernel(unsigned* __restrict__ counts,
                             unsigned* __restrict__ ptot) {
    const int p = blockIdx.x, tid = threadIdx.x;   // 256 threads
    unsigned v[4], s = 0;
    #pragma unroll
    for (int k = 0; k < 4; ++k) {
        v[k] = counts[(size_t)(tid * 4 + k) * NPART + p];
        s += v[k];
    }
    __shared__ unsigned sc[256];
    sc[tid] = s;
    __syncthreads();
    for (int off = 1; off < 256; off <<= 1) {
        unsigned t = (tid >= off) ? sc[tid - off] : 0u;
        __syncthreads();
        sc[tid] += t;
        __syncthreads();
    }
    unsigned run = sc[tid] - s;                    // exclusive
    if (tid == 255) ptot[p] = sc[255];
    #pragma unroll
    for (int k = 0; k < 4; ++k) {
        counts[(size_t)(tid * 4 + k) * NPART + p] = run;
        run += v[k];
    }
}

// ---------------------------------------------------------------------------
// Pass 1.5b: exclusive scan of the 256 partition totals -> part_base[257].
// ---------------------------------------------------------------------------
__global__ void scanB_kernel(const unsigned* __restrict__ ptot,
                             unsigned* __restrict__ part_base) {
    const int tid = threadIdx.x;                   // 256
    unsigned s = ptot[tid];
    __shared__ unsigned sc[256];
    sc[tid] = s;
    __syncthreads();
    for (int off = 1; off < 256; off <<= 1) {
        unsigned t = (tid >= off) ? sc[tid - off] : 0u;
        __syncthreads();
        sc[tid] += t;
        __syncthreads();
    }
    part_base[tid] = sc[tid] - s;
    if (tid == 255) part_base[256] = sc[255];
}

// ---------------------------------------------------------------------------
// Pass 2: reorder each chunk by partition in LDS, write packed 8B entries
// (val f32, row_local<<17 | col) as contiguous per-partition runs.
// Global offset = part_base[p] + within-partition offset.
// ---------------------------------------------------------------------------
__global__ void bin_kernel(const float* __restrict__ A_vals,
                           const int*   __restrict__ A_rows,
                           const int*   __restrict__ A_cols,
                           const unsigned* __restrict__ offsets,
                           const unsigned* __restrict__ part_base,
                           uint2* __restrict__ bins) {
    __shared__ uint2 stage[CHUNK];            // 64 KB
    __shared__ unsigned char spart[CHUNK];    // 8 KB
    __shared__ unsigned h[NPART], loff[NPART], cnt[NPART], goff[NPART];
    const int chunk = blockIdx.x, tid = threadIdx.x;
    h[tid] = 0; cnt[tid] = 0;
    __syncthreads();

    const int base = chunk * CHUNK;
    int rows[P2_PER_T];
    #pragma unroll
    for (int k = 0; k < P2_PER_T; ++k) {
        rows[k] = A_rows[base + k * P2_T + tid];
        atomicAdd(&h[rows[k] >> PART_SH], 1u);
    }
    __syncthreads();
    if (tid == 0) {
        unsigned r = 0;
        for (int p = 0; p < NPART; ++p) { loff[p] = r; r += h[p]; }
    }
    __syncthreads();
    goff[tid] = part_base[tid] + offsets[chunk * NPART + tid];

    #pragma unroll
    for (int k = 0; k < P2_PER_T; ++k) {
        const int i = base + k * P2_T + tid;
        const int row = rows[k];
        const unsigned col = (unsigned)A_cols[i];
        const float v = A_vals[i];
        const int p = row >> PART_SH;
        const unsigned rank = atomicAdd(&cnt[p], 1u);
        const unsigned pos = loff[p] + rank;
        stage[pos] = make_uint2(__float_as_uint(v),
                                ((unsigned)(row & (PART_PIX - 1)) << 17) | col);
        spart[pos] = (unsigned char)p;
    }
    __syncthreads();

    #pragma unroll
    for (int k = 0; k < P2_PER_T; ++k) {
        const int i = k * P2_T + tid;
        const unsigned p = spart[i];
        const unsigned glob = goff[p] + (unsigned)i - loff[p];
        bins[glob] = stage[i];
    }
}

// ---------------------------------------------------------------------------
// Pass 3: one block per partition. Stream the bin coalesced, gather X4[col]
// (L2-resident), accumulate via NATIVE ds_add_f32 (unsafeAtomicAdd — plain
// atomicAdd on LDS float is a CAS retry loop without -munsafe-fp-atomics;
// that retry chain was the 175us / 6500-cyc-per-iter stall). Then write the
// clipped output slice directly. Zero global atomics.
// ---------------------------------------------------------------------------
__global__ void __launch_bounds__(1024)
accum_kernel(const uint2* __restrict__ bins,
             const unsigned* __restrict__ part_base,
             const float4* __restrict__ X4,
             float* __restrict__ out) {
    __shared__ float facc[NB][PART_PIX];
    const int p = blockIdx.x, tid = threadIdx.x;
    ((float*)facc)[tid] = 0.f;
    __syncthreads();

    const unsigned s = part_base[p], e = part_base[p + 1];
    for (unsigned i = s + tid; i < e; i += 1024) {
        const uint2 en = bins[i];
        const float v = __uint_as_float(en.x);
        const unsigned col = en.y & 0x1FFFFu;
        const unsigned rl  = en.y >> 17;
        const float4 x = X4[col];
        unsafeAtomicAdd(&facc[0][rl], v * x.x);
        unsafeAtomicAdd(&facc[1][rl], v * x.y);
        unsafeAtomicAdd(&facc[2][rl], v * x.z);
        unsafeAtomicAdd(&facc[3][rl], v * x.w);
    }
    __syncthreads();

    const int ch = tid >> 8, rl = tid & (PART_PIX - 1);
    const float r = facc[ch][rl];
    out[(size_t)ch * N_PIXK + p * PART_PIX + rl] = fminf(fmaxf(r, 0.f), 1.f);
}

// ------------------------- fallback (round-3 path) -------------------------
#define NXCD 8
#define FP_SCALE 16777216.0f
#define FP_INV   (1.0 / 16777216.0)
__global__ void zero_u64_kernel(unsigned long long* __restrict__ p, int n) {
    int i = blockIdx.x * blockDim.x + threadIdx.x;
    if (i < n) p[i] = 0ULL;
}
__device__ __forceinline__ unsigned get_xcc_id() {
    unsigned x;
    asm volatile("s_getreg_b32 %0, hwreg(HW_REG_XCC_ID, 0, 4)" : "=s"(x));
    return x & (NXCD - 1);
}
__global__ void scatter_kernel(const float*  __restrict__ A_vals,
                               const int*    __restrict__ A_rows,
                               const int*    __restrict__ A_cols,
                               const float4* __restrict__ X4,
                               unsigned long long* __restrict__ rep) {
    unsigned long long* myrep = rep + (size_t)get_xcc_id() * N_PIXK * 2;
    const int stride = gridDim.x * blockDim.x;
    for (int i = blockIdx.x * blockDim.x + threadIdx.x; i < NNZK; i += stride) {
        const float v = A_vals[i];
        const float4 x = X4[A_cols[i]];
        const int r = A_rows[i];
        const int i0 = __float2int_rn(v * x.x * FP_SCALE);
        const int i1 = __float2int_rn(v * x.y * FP_SCALE);
        const int i2 = __float2int_rn(v * x.z * FP_SCALE);
        const int i3 = __float2int_rn(v * x.w * FP_SCALE);
        const unsigned long long w0 =
            ((unsigned long long)(unsigned)i1 << 32) + (unsigned long long)(unsigned)i0;
        const unsigned long long w1 =
            ((unsigned long long)(unsigned)i3 << 32) + (unsigned long long)(unsigned)i2;
        __hip_atomic_fetch_add(&myrep[(size_t)r * 2 + 0], w0,
                               __ATOMIC_RELAXED, __HIP_MEMORY_SCOPE_WORKGROUP);
        __hip_atomic_fetch_add(&myrep[(size_t)r * 2 + 1], w1,
                               __ATOMIC_RELAXED, __HIP_MEMORY_SCOPE_WORKGROUP);
    }
}
__global__ void reduce_clip_kernel(const unsigned long long* __restrict__ rep,
                                   float* __restrict__ out) {
    const int p = blockIdx.x * blockDim.x + threadIdx.x;
    if (p >= N_PIXK) return;
    unsigned long long s0 = 0, s1 = 0;
    #pragma unroll
    for (int x = 0; x < NXCD; ++x) {
        s0 += rep[((size_t)x * N_PIXK + p) * 2 + 0];
        s1 += rep[((size_t)x * N_PIXK + p) * 2 + 1];
    }
    const float c0 = (float)((double)(int)(unsigned)(s0 & 0xffffffffULL) * FP_INV);
    const float c1 = (float)((double)(int)(unsigned)(s0 >> 32)           * FP_INV);
    const float c2 = (float)((double)(int)(unsigned)(s1 & 0xffffffffULL) * FP_INV);
    const float c3 = (float)((double)(int)(unsigned)(s1 >> 32)           * FP_INV);
    out[0 * N_PIXK + p] = fminf(fmaxf(c0, 0.f), 1.f);
    out[1 * N_PIXK + p] = fminf(fmaxf(c1, 0.f), 1.f);
    out[2 * N_PIXK + p] = fminf(fmaxf(c2, 0.f), 1.f);
    out[3 * N_PIXK + p] = fminf(fmaxf(c3, 0.f), 1.f);
}

extern "C" void kernel_launch(void* const* d_in, const int* in_sizes, int n_in,
                              void* d_out, int out_size, void* d_ws, size_t ws_size,
                              hipStream_t stream) {
    const float* sin_fan = (const float*)d_in[0];
    const float* cosv    = (const float*)d_in[1];
    const float* filt    = (const float*)d_in[2];
    const float* A_vals  = (const float*)d_in[3];
    const int*   A_rows  = (const int*)d_in[4];
    const int*   A_cols  = (const int*)d_in[5];
    float* out = (float*)d_out;

    // ws layout for sort path:
    //   [0, 2MB)            X          (N_COLS*4 floats = 2,056,320 B)
    //   [2MB, 3MB)          counts     (NCHUNK*NPART u32 = 1 MB)
    //   [3MB, +2KB)         part_base  (257 u32)
    //   [3MB+2KB, +2KB)     ptot       (256 u32)
    //   [3MB+4KB, +64MB)    bins       (NNZK uint2 = 64 MB)
    const size_t MB = 1024 * 1024;
    const size_t need_sort = 3 * MB + 4096 + (size_t)NNZK * sizeof(uint2);

    if (ws_size >= need_sort) {
        float*    X      = (float*)d_ws;
        unsigned* counts = (unsigned*)((char*)d_ws + 2 * MB);
        unsigned* pbase  = (unsigned*)((char*)d_ws + 3 * MB);
        unsigned* ptot   = (unsigned*)((char*)d_ws + 3 * MB + 2048);
        uint2*    bins   = (uint2*)((char*)d_ws + 3 * MB + 4096);

        filt_kernel<<<NB * N_ANG, 256, 0, stream>>>(sin_fan, cosv, filt, X);
        hist_kernel<<<NCHUNK, P2_T, 0, stream>>>(A_rows, counts);
        scanA_kernel<<<NPART, 256, 0, stream>>>(counts, ptot);
        scanB_kernel<<<1, 256, 0, stream>>>(ptot, pbase);
        bin_kernel<<<NCHUNK, P2_T, 0, stream>>>(A_vals, A_rows, A_cols, counts,
                                                pbase, bins);
        accum_kernel<<<NPART, 1024, 0, stream>>>(bins, pbase, (const float4*)X, out);
    } else {
        // fallback: per-XCD replica atomic path (needs ~10 MB)
        unsigned long long* rep = (unsigned long long*)d_ws;
        const size_t rep_bytes = (size_t)NXCD * N_PIXK * 2 * sizeof(unsigned long long);
        float* X = (float*)((char*)d_ws + rep_bytes);
        const int nrep = NXCD * N_PIXK * 2;
        zero_u64_kernel<<<(nrep + 255) / 256, 256, 0, stream>>>(rep, nrep);
        filt_kernel<<<NB * N_ANG, 256, 0, stream>>>(sin_fan, cosv, filt, X);
        scatter_kernel<<<4096, 256, 0, stream>>>(A_vals, A_rows, A_cols,
                                                 (const float4*)X, rep);
        reduce_clip_kernel<<<(N_PIXK + 255) / 256, 256, 0, stream>>>(rep, out);
    }
}

// Round 6
// 137.606 us; speedup vs baseline: 11.8535x; 1.9424x over previous
//
#include <hip/hip_runtime.h>
#include <stdint.h>

#define N_ANG    360
#define N_DET    357
#define FILT_LEN 713
#define N_COLS   (N_ANG * N_DET)      // 128520 < 2^17
#define N_PIXK   65536
#define NNZK     8388608
#define NB       4

#define NPART    256
#define PART_SH  8                    // partition = row >> 8
#define PART_PIX 256                  // pixels per partition
#define CHUNK    8192                 // nnz per chunk/block in passes 1-2
#define NCHUNK   (NNZK / CHUNK)       // 1024, exact
#define P2_T     256
#define P2_PER_T (CHUNK / P2_T)       // 32

#define FPS      67108864.0f          // 2^26 fixed-point scale
#define FPS_INV  (1.0f / 67108864.0f)

// ---------------------------------------------------------------------------
// Stage 1: r = sin_fan * cos, SAME conv len-713 along detector axis.
// Filter covers whole row: F[b,a,d] = sum_j r[j] * filt[356 + j - d].
// X written [col][b] so accum gathers one float4 per nnz.
// ---------------------------------------------------------------------------
__global__ void filt_kernel(const float* __restrict__ sin_fan,
                            const float* __restrict__ cosv,
                            const float* __restrict__ filt,
                            float* __restrict__ X) {
    __shared__ float s_r[N_DET];
    __shared__ float s_f[FILT_LEN];
    const int blk = blockIdx.x;            // b*N_ANG + a
    const int b   = blk / N_ANG;
    const int a   = blk % N_ANG;
    const int tid = threadIdx.x;

    for (int i = tid; i < N_DET; i += blockDim.x)
        s_r[i] = sin_fan[(size_t)(b * N_ANG + a) * N_DET + i] * cosv[a * N_DET + i];
    for (int i = tid; i < FILT_LEN; i += blockDim.x)
        s_f[i] = filt[i];
    __syncthreads();

    for (int d = tid; d < N_DET; d += blockDim.x) {
        float acc = 0.f;
        const float* fp = &s_f[356 - d];
        #pragma unroll 7
        for (int j = 0; j < N_DET; ++j)
            acc = fmaf(s_r[j], fp[j], acc);
        X[(size_t)(a * N_DET + d) * NB + b] = acc;
    }
}

// ---------------------------------------------------------------------------
// Pass 1: per-chunk partition histogram (native ds_add_u32).
// counts layout: [chunk][part].
// ---------------------------------------------------------------------------
__global__ void hist_kernel(const int* __restrict__ A_rows,
                            unsigned* __restrict__ counts) {
    __shared__ unsigned h[NPART];
    const int chunk = blockIdx.x, tid = threadIdx.x;
    h[tid] = 0;
    __syncthreads();
    const int base = chunk * CHUNK;
    #pragma unroll
    for (int k = 0; k < P2_PER_T; ++k) {
        int row = A_rows[base + k * P2_T + tid];
        atomicAdd(&h[row >> PART_SH], 1u);
    }
    __syncthreads();
    counts[chunk * NPART + tid] = h[tid];
}

// ---------------------------------------------------------------------------
// Pass 1.5a: per-partition exclusive prefix over the 1024 chunks.
// Block p owns partition p; thread t owns chunks [4t, 4t+4).
// ---------------------------------------------------------------------------
__global__ void scanA_kernel(unsigned* __restrict__ counts,
                             unsigned* __restrict__ ptot) {
    const int p = blockIdx.x, tid = threadIdx.x;   // 256 threads
    unsigned v[4], s = 0;
    #pragma unroll
    for (int k = 0; k < 4; ++k) {
        v[k] = counts[(size_t)(tid * 4 + k) * NPART + p];
        s += v[k];
    }
    __shared__ unsigned sc[256];
    sc[tid] = s;
    __syncthreads();
    for (int off = 1; off < 256; off <<= 1) {
        unsigned t = (tid >= off) ? sc[tid - off] : 0u;
        __syncthreads();
        sc[tid] += t;
        __syncthreads();
    }
    unsigned run = sc[tid] - s;                    // exclusive
    if (tid == 255) ptot[p] = sc[255];
    #pragma unroll
    for (int k = 0; k < 4; ++k) {
        counts[(size_t)(tid * 4 + k) * NPART + p] = run;
        run += v[k];
    }
}

// ---------------------------------------------------------------------------
// Pass 1.5b: exclusive scan of the 256 partition totals -> part_base[257].
// ---------------------------------------------------------------------------
__global__ void scanB_kernel(const unsigned* __restrict__ ptot,
                             unsigned* __restrict__ part_base) {
    const int tid = threadIdx.x;                   // 256
    unsigned s = ptot[tid];
    __shared__ unsigned sc[256];
    sc[tid] = s;
    __syncthreads();
    for (int off = 1; off < 256; off <<= 1) {
        unsigned t = (tid >= off) ? sc[tid - off] : 0u;
        __syncthreads();
        sc[tid] += t;
        __syncthreads();
    }
    part_base[tid] = sc[tid] - s;
    if (tid == 255) part_base[256] = sc[255];
}

// ---------------------------------------------------------------------------
// Pass 2: reorder each chunk by partition in LDS, write packed 8B entries
// (val f32, row_local<<17 | col) as contiguous per-partition runs.
// ---------------------------------------------------------------------------
__global__ void bin_kernel(const float* __restrict__ A_vals,
                           const int*   __restrict__ A_rows,
                           const int*   __restrict__ A_cols,
                           const unsigned* __restrict__ offsets,
                           const unsigned* __restrict__ part_base,
                           uint2* __restrict__ bins) {
    __shared__ uint2 stage[CHUNK];            // 64 KB
    __shared__ unsigned char spart[CHUNK];    // 8 KB
    __shared__ unsigned h[NPART], loff[NPART], cnt[NPART], goff[NPART];
    const int chunk = blockIdx.x, tid = threadIdx.x;
    h[tid] = 0; cnt[tid] = 0;
    __syncthreads();

    const int base = chunk * CHUNK;
    int rows[P2_PER_T];
    #pragma unroll
    for (int k = 0; k < P2_PER_T; ++k) {
        rows[k] = A_rows[base + k * P2_T + tid];
        atomicAdd(&h[rows[k] >> PART_SH], 1u);
    }
    __syncthreads();
    if (tid == 0) {
        unsigned r = 0;
        for (int p = 0; p < NPART; ++p) { loff[p] = r; r += h[p]; }
    }
    __syncthreads();
    goff[tid] = part_base[tid] + offsets[chunk * NPART + tid];

    #pragma unroll
    for (int k = 0; k < P2_PER_T; ++k) {
        const int i = base + k * P2_T + tid;
        const int row = rows[k];
        const unsigned col = (unsigned)A_cols[i];
        const float v = A_vals[i];
        const int p = row >> PART_SH;
        const unsigned rank = atomicAdd(&cnt[p], 1u);
        const unsigned pos = loff[p] + rank;
        stage[pos] = make_uint2(__float_as_uint(v),
                                ((unsigned)(row & (PART_PIX - 1)) << 17) | col);
        spart[pos] = (unsigned char)p;
    }
    __syncthreads();

    #pragma unroll
    for (int k = 0; k < P2_PER_T; ++k) {
        const int i = k * P2_T + tid;
        const unsigned p = spart[i];
        const unsigned glob = goff[p] + (unsigned)i - loff[p];
        bins[glob] = stage[i];
    }
}

// ---------------------------------------------------------------------------
// Pass 3: one block per partition. Stream the bin coalesced, gather X4[col]
// (L2-resident), accumulate via NATIVE INTEGER ds_add_u32 in 2^26 fixed
// point. Rationale: float atomicAdd/unsafeAtomicAdd on LDS both expand to a
// CAS retry loop (unsafe fast path is global-AS only); 16 waves hammering
// 1024 words caused a retry storm (13k cyc/iter, VALUBusy 1.3%). Integer
// LDS atomics are single-instruction fire-and-forget — same class as the
// hist kernel, which runs at full speed. Max |sum| < 2 -> 2^26 scale is
// overflow-safe (1.3e8 << 2^31); rounding error ~1e-5 vs 6.3e-4 threshold.
// facc layout [ch][rl]: bank = rl&31 -> ~2 lanes/bank (free, m136).
// ---------------------------------------------------------------------------
__global__ void __launch_bounds__(1024)
accum_kernel(const uint2* __restrict__ bins,
             const unsigned* __restrict__ part_base,
             const float4* __restrict__ X4,
             float* __restrict__ out) {
    __shared__ unsigned iacc[NB][PART_PIX];
    const int p = blockIdx.x, tid = threadIdx.x;
    ((unsigned*)iacc)[tid] = 0u;
    __syncthreads();

    const unsigned s = part_base[p], e = part_base[p + 1];
    #pragma unroll 4
    for (unsigned i = s + tid; i < e; i += 1024) {
        const uint2 en = bins[i];
        const float v = __uint_as_float(en.x);
        const unsigned col = en.y & 0x1FFFFu;
        const unsigned rl  = en.y >> 17;
        const float4 x = X4[col];
        atomicAdd(&iacc[0][rl], (unsigned)__float2int_rn(v * x.x * FPS));
        atomicAdd(&iacc[1][rl], (unsigned)__float2int_rn(v * x.y * FPS));
        atomicAdd(&iacc[2][rl], (unsigned)__float2int_rn(v * x.z * FPS));
        atomicAdd(&iacc[3][rl], (unsigned)__float2int_rn(v * x.w * FPS));
    }
    __syncthreads();

    const int ch = tid >> 8, rl = tid & (PART_PIX - 1);
    const float r = (float)(int)iacc[ch][rl] * FPS_INV;
    out[(size_t)ch * N_PIXK + p * PART_PIX + rl] = fminf(fmaxf(r, 0.f), 1.f);
}

// ------------------------- fallback (round-3 path) -------------------------
#define NXCD 8
#define FP_SCALE 16777216.0f
#define FP_INV   (1.0 / 16777216.0)
__global__ void zero_u64_kernel(unsigned long long* __restrict__ p, int n) {
    int i = blockIdx.x * blockDim.x + threadIdx.x;
    if (i < n) p[i] = 0ULL;
}
__device__ __forceinline__ unsigned get_xcc_id() {
    unsigned x;
    asm volatile("s_getreg_b32 %0, hwreg(HW_REG_XCC_ID, 0, 4)" : "=s"(x));
    return x & (NXCD - 1);
}
__global__ void scatter_kernel(const float*  __restrict__ A_vals,
                               const int*    __restrict__ A_rows,
                               const int*    __restrict__ A_cols,
                               const float4* __restrict__ X4,
                               unsigned long long* __restrict__ rep) {
    unsigned long long* myrep = rep + (size_t)get_xcc_id() * N_PIXK * 2;
    const int stride = gridDim.x * blockDim.x;
    for (int i = blockIdx.x * blockDim.x + threadIdx.x; i < NNZK; i += stride) {
        const float v = A_vals[i];
        const float4 x = X4[A_cols[i]];
        const int r = A_rows[i];
        const int i0 = __float2int_rn(v * x.x * FP_SCALE);
        const int i1 = __float2int_rn(v * x.y * FP_SCALE);
        const int i2 = __float2int_rn(v * x.z * FP_SCALE);
        const int i3 = __float2int_rn(v * x.w * FP_SCALE);
        const unsigned long long w0 =
            ((unsigned long long)(unsigned)i1 << 32) + (unsigned long long)(unsigned)i0;
        const unsigned long long w1 =
            ((unsigned long long)(unsigned)i3 << 32) + (unsigned long long)(unsigned)i2;
        __hip_atomic_fetch_add(&myrep[(size_t)r * 2 + 0], w0,
                               __ATOMIC_RELAXED, __HIP_MEMORY_SCOPE_WORKGROUP);
        __hip_atomic_fetch_add(&myrep[(size_t)r * 2 + 1], w1,
                               __ATOMIC_RELAXED, __HIP_MEMORY_SCOPE_WORKGROUP);
    }
}
__global__ void reduce_clip_kernel(const unsigned long long* __restrict__ rep,
                                   float* __restrict__ out) {
    const int p = blockIdx.x * blockDim.x + threadIdx.x;
    if (p >= N_PIXK) return;
    unsigned long long s0 = 0, s1 = 0;
    #pragma unroll
    for (int x = 0; x < NXCD; ++x) {
        s0 += rep[((size_t)x * N_PIXK + p) * 2 + 0];
        s1 += rep[((size_t)x * N_PIXK + p) * 2 + 1];
    }
    const float c0 = (float)((double)(int)(unsigned)(s0 & 0xffffffffULL) * FP_INV);
    const float c1 = (float)((double)(int)(unsigned)(s0 >> 32)           * FP_INV);
    const float c2 = (float)((double)(int)(unsigned)(s1 & 0xffffffffULL) * FP_INV);
    const float c3 = (float)((double)(int)(unsigned)(s1 >> 32)           * FP_INV);
    out[0 * N_PIXK + p] = fminf(fmaxf(c0, 0.f), 1.f);
    out[1 * N_PIXK + p] = fminf(fmaxf(c1, 0.f), 1.f);
    out[2 * N_PIXK + p] = fminf(fmaxf(c2, 0.f), 1.f);
    out[3 * N_PIXK + p] = fminf(fmaxf(c3, 0.f), 1.f);
}

extern "C" void kernel_launch(void* const* d_in, const int* in_sizes, int n_in,
                              void* d_out, int out_size, void* d_ws, size_t ws_size,
                              hipStream_t stream) {
    const float* sin_fan = (const float*)d_in[0];
    const float* cosv    = (const float*)d_in[1];
    const float* filt    = (const float*)d_in[2];
    const float* A_vals  = (const float*)d_in[3];
    const int*   A_rows  = (const int*)d_in[4];
    const int*   A_cols  = (const int*)d_in[5];
    float* out = (float*)d_out;

    // ws layout for sort path:
    //   [0, 2MB)            X          (N_COLS*4 floats = 2,056,320 B)
    //   [2MB, 3MB)          counts     (NCHUNK*NPART u32 = 1 MB)
    //   [3MB, +2KB)         part_base  (257 u32)
    //   [3MB+2KB, +2KB)     ptot       (256 u32)
    //   [3MB+4KB, +64MB)    bins       (NNZK uint2 = 64 MB)
    const size_t MB = 1024 * 1024;
    const size_t need_sort = 3 * MB + 4096 + (size_t)NNZK * sizeof(uint2);

    if (ws_size >= need_sort) {
        float*    X      = (float*)d_ws;
        unsigned* counts = (unsigned*)((char*)d_ws + 2 * MB);
        unsigned* pbase  = (unsigned*)((char*)d_ws + 3 * MB);
        unsigned* ptot   = (unsigned*)((char*)d_ws + 3 * MB + 2048);
        uint2*    bins   = (uint2*)((char*)d_ws + 3 * MB + 4096);

        filt_kernel<<<NB * N_ANG, 256, 0, stream>>>(sin_fan, cosv, filt, X);
        hist_kernel<<<NCHUNK, P2_T, 0, stream>>>(A_rows, counts);
        scanA_kernel<<<NPART, 256, 0, stream>>>(counts, ptot);
        scanB_kernel<<<1, 256, 0, stream>>>(ptot, pbase);
        bin_kernel<<<NCHUNK, P2_T, 0, stream>>>(A_vals, A_rows, A_cols, counts,
                                                pbase, bins);
        accum_kernel<<<NPART, 1024, 0, stream>>>(bins, pbase, (const float4*)X, out);
    } else {
        // fallback: per-XCD replica atomic path (needs ~10 MB)
        unsigned long long* rep = (unsigned long long*)d_ws;
        const size_t rep_bytes = (size_t)NXCD * N_PIXK * 2 * sizeof(unsigned long long);
        float* X = (float*)((char*)d_ws + rep_bytes);
        const int nrep = NXCD * N_PIXK * 2;
        zero_u64_kernel<<<(nrep + 255) / 256, 256, 0, stream>>>(rep, nrep);
        filt_kernel<<<NB * N_ANG, 256, 0, stream>>>(sin_fan, cosv, filt, X);
        scatter_kernel<<<4096, 256, 0, stream>>>(A_vals, A_rows, A_cols,
                                                 (const float4*)X, rep);
        reduce_clip_kernel<<<(N_PIXK + 255) / 256, 256, 0, stream>>>(rep, out);
    }
}

// Round 7
// 128.167 us; speedup vs baseline: 12.7264x; 1.0736x over previous
//
#include <hip/hip_runtime.h>
#include <stdint.h>

#define N_ANG    360
#define N_DET    357
#define FILT_LEN 713
#define N_COLS   (N_ANG * N_DET)      // 128520 < 2^17
#define N_PIXK   65536
#define NNZK     8388608
#define NB       4

#define NPART    256
#define PART_SH  8                    // partition = row >> 8
#define PART_PIX 256                  // pixels per partition
#define CHUNK    8192                 // nnz per chunk/block in passes 1-2
#define NCHUNK   (NNZK / CHUNK)       // 1024, exact
#define P1_T     256
#define P1_PER_T (CHUNK / P1_T)       // 32
#define P2_T     1024
#define P2_PER_T (CHUNK / P2_T)       // 8

#define ACC_SPLIT 4                   // sub-blocks per partition in accum

#define FPS      67108864.0f          // 2^26 fixed-point scale
#define FPS_INV  (1.0f / 67108864.0f)

// ---------------------------------------------------------------------------
// Stage 1: r = sin_fan * cos, SAME conv len-713 along detector axis.
// Filter covers whole row: F[b,a,d] = sum_j r[j] * filt[356 + j - d].
// X written [col][b] so accum gathers one float4 per nnz.
// ---------------------------------------------------------------------------
__global__ void filt_kernel(const float* __restrict__ sin_fan,
                            const float* __restrict__ cosv,
                            const float* __restrict__ filt,
                            float* __restrict__ X) {
    __shared__ float s_r[N_DET];
    __shared__ float s_f[FILT_LEN];
    const int blk = blockIdx.x;            // b*N_ANG + a
    const int b   = blk / N_ANG;
    const int a   = blk % N_ANG;
    const int tid = threadIdx.x;

    for (int i = tid; i < N_DET; i += blockDim.x)
        s_r[i] = sin_fan[(size_t)(b * N_ANG + a) * N_DET + i] * cosv[a * N_DET + i];
    for (int i = tid; i < FILT_LEN; i += blockDim.x)
        s_f[i] = filt[i];
    __syncthreads();

    for (int d = tid; d < N_DET; d += blockDim.x) {
        float acc = 0.f;
        const float* fp = &s_f[356 - d];
        #pragma unroll 7
        for (int j = 0; j < N_DET; ++j)
            acc = fmaf(s_r[j], fp[j], acc);
        X[(size_t)(a * N_DET + d) * NB + b] = acc;
    }
}

// ---------------------------------------------------------------------------
// Pass 1: per-chunk partition histogram (native ds_add_u32).
// counts layout: [chunk][part].
// ---------------------------------------------------------------------------
__global__ void hist_kernel(const int* __restrict__ A_rows,
                            unsigned* __restrict__ counts) {
    __shared__ unsigned h[NPART];
    const int chunk = blockIdx.x, tid = threadIdx.x;
    h[tid] = 0;
    __syncthreads();
    const int base = chunk * CHUNK;
    #pragma unroll
    for (int k = 0; k < P1_PER_T; ++k) {
        int row = A_rows[base + k * P1_T + tid];
        atomicAdd(&h[row >> PART_SH], 1u);
    }
    __syncthreads();
    counts[chunk * NPART + tid] = h[tid];
}

// ---------------------------------------------------------------------------
// Pass 1.5a: per-partition exclusive prefix over the 1024 chunks.
// ---------------------------------------------------------------------------
__global__ void scanA_kernel(unsigned* __restrict__ counts,
                             unsigned* __restrict__ ptot) {
    const int p = blockIdx.x, tid = threadIdx.x;   // 256 threads
    unsigned v[4], s = 0;
    #pragma unroll
    for (int k = 0; k < 4; ++k) {
        v[k] = counts[(size_t)(tid * 4 + k) * NPART + p];
        s += v[k];
    }
    __shared__ unsigned sc[256];
    sc[tid] = s;
    __syncthreads();
    for (int off = 1; off < 256; off <<= 1) {
        unsigned t = (tid >= off) ? sc[tid - off] : 0u;
        __syncthreads();
        sc[tid] += t;
        __syncthreads();
    }
    unsigned run = sc[tid] - s;                    // exclusive
    if (tid == 255) ptot[p] = sc[255];
    #pragma unroll
    for (int k = 0; k < 4; ++k) {
        counts[(size_t)(tid * 4 + k) * NPART + p] = run;
        run += v[k];
    }
}

// ---------------------------------------------------------------------------
// Pass 1.5b: exclusive scan of the 256 partition totals -> part_base[257].
// ---------------------------------------------------------------------------
__global__ void scanB_kernel(const unsigned* __restrict__ ptot,
                             unsigned* __restrict__ part_base) {
    const int tid = threadIdx.x;                   // 256
    unsigned s = ptot[tid];
    __shared__ unsigned sc[256];
    sc[tid] = s;
    __syncthreads();
    for (int off = 1; off < 256; off <<= 1) {
        unsigned t = (tid >= off) ? sc[tid - off] : 0u;
        __syncthreads();
        sc[tid] += t;
        __syncthreads();
    }
    part_base[tid] = sc[tid] - s;
    if (tid == 255) part_base[256] = sc[255];
}

// ---------------------------------------------------------------------------
// Pass 2: reorder each chunk by partition in LDS, write packed 8B entries
// (val f32, row_local<<17 | col) as contiguous per-partition runs.
// 1024 threads/block: 76KB LDS allows 2 blocks/CU -> 32 waves/CU (100% occ);
// the previous 256-thread version capped at 8 waves/CU (17% observed) and
// ran latency-bound at 2 TB/s. loff prefix is a parallel Hillis-Steele scan.
// ---------------------------------------------------------------------------
__global__ void __launch_bounds__(1024)
bin_kernel(const float* __restrict__ A_vals,
           const int*   __restrict__ A_rows,
           const int*   __restrict__ A_cols,
           const unsigned* __restrict__ offsets,
           const unsigned* __restrict__ part_base,
           uint2* __restrict__ bins) {
    __shared__ uint2 stage[CHUNK];            // 64 KB
    __shared__ unsigned char spart[CHUNK];    // 8 KB
    __shared__ unsigned loff[NPART], cnt[NPART], goff[NPART];
    const int chunk = blockIdx.x, tid = threadIdx.x;   // 1024
    if (tid < NPART) cnt[tid] = 0;
    if (tid >= NPART && tid < 2 * NPART) loff[tid - NPART] = 0;
    __syncthreads();

    const int base = chunk * CHUNK;
    int rows[P2_PER_T];
    #pragma unroll
    for (int k = 0; k < P2_PER_T; ++k) {
        rows[k] = A_rows[base + k * P2_T + tid];
        atomicAdd(&loff[rows[k] >> PART_SH], 1u);      // histogram into loff
    }
    __syncthreads();

    // exclusive scan loff in place (Hillis-Steele, first 256 threads work,
    // all threads hit the barriers)
    unsigned hv = 0;
    if (tid < NPART) hv = loff[tid];
    for (int off = 1; off < NPART; off <<= 1) {
        unsigned t = 0;
        if (tid < NPART && tid >= off) t = loff[tid - off];
        __syncthreads();
        if (tid < NPART) loff[tid] += t;
        __syncthreads();
    }
    if (tid < NPART) {
        loff[tid] -= hv;                               // inclusive -> exclusive
        goff[tid] = part_base[tid] + offsets[chunk * NPART + tid];
    }
    __syncthreads();

    #pragma unroll
    for (int k = 0; k < P2_PER_T; ++k) {
        const int i = base + k * P2_T + tid;
        const int row = rows[k];
        const unsigned col = (unsigned)A_cols[i];
        const float v = A_vals[i];
        const int p = row >> PART_SH;
        const unsigned rank = atomicAdd(&cnt[p], 1u);
        const unsigned pos = loff[p] + rank;
        stage[pos] = make_uint2(__float_as_uint(v),
                                ((unsigned)(row & (PART_PIX - 1)) << 17) | col);
        spart[pos] = (unsigned char)p;
    }
    __syncthreads();

    #pragma unroll
    for (int k = 0; k < P2_PER_T; ++k) {
        const int i = k * P2_T + tid;
        const unsigned p = spart[i];
        const unsigned glob = goff[p] + (unsigned)i - loff[p];
        bins[glob] = stage[i];
    }
}

// ---------------------------------------------------------------------------
// Pass 3 (split): 4 sub-blocks per partition, each accumulates its quarter of
// the bin range into private LDS u32 accumulators (native ds_add_u32, 2^26
// fixed point), then writes exact u32 partials — no atomics, no zero-init.
// ---------------------------------------------------------------------------
__global__ void __launch_bounds__(1024)
accum4_kernel(const uint2* __restrict__ bins,
              const unsigned* __restrict__ part_base,
              const float4* __restrict__ X4,
              unsigned* __restrict__ partial) {
    __shared__ unsigned iacc[NB * PART_PIX];
    const int bp = blockIdx.x;
    const int p = bp >> 2, j = bp & 3;
    const int tid = threadIdx.x;
    iacc[tid] = 0u;
    __syncthreads();

    const unsigned s = part_base[p], e = part_base[p + 1];
    const unsigned len = e - s;
    const unsigned q = (len + ACC_SPLIT - 1) / ACC_SPLIT;
    const unsigned qs = s + j * q;
    const unsigned qe = min(qs + q, e);

    #pragma unroll 4
    for (unsigned i = qs + tid; i < qe; i += 1024) {
        const uint2 en = bins[i];
        const float v = __uint_as_float(en.x);
        const unsigned col = en.y & 0x1FFFFu;
        const unsigned rl  = en.y >> 17;
        const float4 x = X4[col];
        atomicAdd(&iacc[0 * PART_PIX + rl], (unsigned)__float2int_rn(v * x.x * FPS));
        atomicAdd(&iacc[1 * PART_PIX + rl], (unsigned)__float2int_rn(v * x.y * FPS));
        atomicAdd(&iacc[2 * PART_PIX + rl], (unsigned)__float2int_rn(v * x.z * FPS));
        atomicAdd(&iacc[3 * PART_PIX + rl], (unsigned)__float2int_rn(v * x.w * FPS));
    }
    __syncthreads();

    partial[((size_t)j * NPART + p) * 1024 + tid] = iacc[tid];
}

// ---------------------------------------------------------------------------
// Pass 3b: sum the 4 partials (u32, exact), decode fixed point, clip, write.
// g indexes [p][ch][rl]; out layout is [ch][p*256+rl].
// ---------------------------------------------------------------------------
__global__ void reduce4_kernel(const unsigned* __restrict__ partial,
                               float* __restrict__ out) {
    const int g = blockIdx.x * blockDim.x + threadIdx.x;   // 0 .. 256*1024-1
    const int p = g >> 10, t = g & 1023;
    const int ch = t >> 8, rl = t & (PART_PIX - 1);
    unsigned s = 0;
    #pragma unroll
    for (int j = 0; j < ACC_SPLIT; ++j)
        s += partial[((size_t)j * NPART + p) * 1024 + t];
    const float r = (float)(int)s * FPS_INV;
    out[(size_t)ch * N_PIXK + p * PART_PIX + rl] = fminf(fmaxf(r, 0.f), 1.f);
}

// ---------------------------------------------------------------------------
// Pass 3 (single, fallback when ws lacks room for partials).
// ---------------------------------------------------------------------------
__global__ void __launch_bounds__(1024)
accum_kernel(const uint2* __restrict__ bins,
             const unsigned* __restrict__ part_base,
             const float4* __restrict__ X4,
             float* __restrict__ out) {
    __shared__ unsigned iacc[NB][PART_PIX];
    const int p = blockIdx.x, tid = threadIdx.x;
    ((unsigned*)iacc)[tid] = 0u;
    __syncthreads();

    const unsigned s = part_base[p], e = part_base[p + 1];
    #pragma unroll 4
    for (unsigned i = s + tid; i < e; i += 1024) {
        const uint2 en = bins[i];
        const float v = __uint_as_float(en.x);
        const unsigned col = en.y & 0x1FFFFu;
        const unsigned rl  = en.y >> 17;
        const float4 x = X4[col];
        atomicAdd(&iacc[0][rl], (unsigned)__float2int_rn(v * x.x * FPS));
        atomicAdd(&iacc[1][rl], (unsigned)__float2int_rn(v * x.y * FPS));
        atomicAdd(&iacc[2][rl], (unsigned)__float2int_rn(v * x.z * FPS));
        atomicAdd(&iacc[3][rl], (unsigned)__float2int_rn(v * x.w * FPS));
    }
    __syncthreads();

    const int ch = tid >> 8, rl = tid & (PART_PIX - 1);
    const float r = (float)(int)iacc[ch][rl] * FPS_INV;
    out[(size_t)ch * N_PIXK + p * PART_PIX + rl] = fminf(fmaxf(r, 0.f), 1.f);
}

// ------------------------- fallback (round-3 path) -------------------------
#define NXCD 8
#define FP_SCALE 16777216.0f
#define FP_INV   (1.0 / 16777216.0)
__global__ void zero_u64_kernel(unsigned long long* __restrict__ p, int n) {
    int i = blockIdx.x * blockDim.x + threadIdx.x;
    if (i < n) p[i] = 0ULL;
}
__device__ __forceinline__ unsigned get_xcc_id() {
    unsigned x;
    asm volatile("s_getreg_b32 %0, hwreg(HW_REG_XCC_ID, 0, 4)" : "=s"(x));
    return x & (NXCD - 1);
}
__global__ void scatter_kernel(const float*  __restrict__ A_vals,
                               const int*    __restrict__ A_rows,
                               const int*    __restrict__ A_cols,
                               const float4* __restrict__ X4,
                               unsigned long long* __restrict__ rep) {
    unsigned long long* myrep = rep + (size_t)get_xcc_id() * N_PIXK * 2;
    const int stride = gridDim.x * blockDim.x;
    for (int i = blockIdx.x * blockDim.x + threadIdx.x; i < NNZK; i += stride) {
        const float v = A_vals[i];
        const float4 x = X4[A_cols[i]];
        const int r = A_rows[i];
        const int i0 = __float2int_rn(v * x.x * FP_SCALE);
        const int i1 = __float2int_rn(v * x.y * FP_SCALE);
        const int i2 = __float2int_rn(v * x.z * FP_SCALE);
        const int i3 = __float2int_rn(v * x.w * FP_SCALE);
        const unsigned long long w0 =
            ((unsigned long long)(unsigned)i1 << 32) + (unsigned long long)(unsigned)i0;
        const unsigned long long w1 =
            ((unsigned long long)(unsigned)i3 << 32) + (unsigned long long)(unsigned)i2;
        __hip_atomic_fetch_add(&myrep[(size_t)r * 2 + 0], w0,
                               __ATOMIC_RELAXED, __HIP_MEMORY_SCOPE_WORKGROUP);
        __hip_atomic_fetch_add(&myrep[(size_t)r * 2 + 1], w1,
                               __ATOMIC_RELAXED, __HIP_MEMORY_SCOPE_WORKGROUP);
    }
}
__global__ void reduce_clip_kernel(const unsigned long long* __restrict__ rep,
                                   float* __restrict__ out) {
    const int p = blockIdx.x * blockDim.x + threadIdx.x;
    if (p >= N_PIXK) return;
    unsigned long long s0 = 0, s1 = 0;
    #pragma unroll
    for (int x = 0; x < NXCD; ++x) {
        s0 += rep[((size_t)x * N_PIXK + p) * 2 + 0];
        s1 += rep[((size_t)x * N_PIXK + p) * 2 + 1];
    }
    const float c0 = (float)((double)(int)(unsigned)(s0 & 0xffffffffULL) * FP_INV);
    const float c1 = (float)((double)(int)(unsigned)(s0 >> 32)           * FP_INV);
    const float c2 = (float)((double)(int)(unsigned)(s1 & 0xffffffffULL) * FP_INV);
    const float c3 = (float)((double)(int)(unsigned)(s1 >> 32)           * FP_INV);
    out[0 * N_PIXK + p] = fminf(fmaxf(c0, 0.f), 1.f);
    out[1 * N_PIXK + p] = fminf(fmaxf(c1, 0.f), 1.f);
    out[2 * N_PIXK + p] = fminf(fmaxf(c2, 0.f), 1.f);
    out[3 * N_PIXK + p] = fminf(fmaxf(c3, 0.f), 1.f);
}

extern "C" void kernel_launch(void* const* d_in, const int* in_sizes, int n_in,
                              void* d_out, int out_size, void* d_ws, size_t ws_size,
                              hipStream_t stream) {
    const float* sin_fan = (const float*)d_in[0];
    const float* cosv    = (const float*)d_in[1];
    const float* filt    = (const float*)d_in[2];
    const float* A_vals  = (const float*)d_in[3];
    const int*   A_rows  = (const int*)d_in[4];
    const int*   A_cols  = (const int*)d_in[5];
    float* out = (float*)d_out;

    // ws layout for sort path:
    //   [0, 2MB)            X          (N_COLS*4 floats = 2,056,320 B)
    //   [2MB, 3MB)          counts     (NCHUNK*NPART u32 = 1 MB)
    //   [3MB, +2KB)         part_base  (257 u32)
    //   [3MB+2KB, +2KB)     ptot       (256 u32)
    //   [3MB+4KB, +64MB)    bins       (NNZK uint2 = 64 MB)
    //   [.., +4MB)          partial    (4 * 256 * 1024 u32 = 4 MB) [optional]
    const size_t MB = 1024 * 1024;
    const size_t need_sort  = 3 * MB + 4096 + (size_t)NNZK * sizeof(uint2);
    const size_t need_split = need_sort + (size_t)ACC_SPLIT * NPART * 1024 * 4;

    if (ws_size >= need_sort) {
        float*    X      = (float*)d_ws;
        unsigned* counts = (unsigned*)((char*)d_ws + 2 * MB);
        unsigned* pbase  = (unsigned*)((char*)d_ws + 3 * MB);
        unsigned* ptot   = (unsigned*)((char*)d_ws + 3 * MB + 2048);
        uint2*    bins   = (uint2*)((char*)d_ws + 3 * MB + 4096);
        unsigned* partial= (unsigned*)((char*)d_ws + need_sort);

        filt_kernel<<<NB * N_ANG, 256, 0, stream>>>(sin_fan, cosv, filt, X);
        hist_kernel<<<NCHUNK, P1_T, 0, stream>>>(A_rows, counts);
        scanA_kernel<<<NPART, 256, 0, stream>>>(counts, ptot);
        scanB_kernel<<<1, 256, 0, stream>>>(ptot, pbase);
        bin_kernel<<<NCHUNK, P2_T, 0, stream>>>(A_vals, A_rows, A_cols, counts,
                                                pbase, bins);
        if (ws_size >= need_split) {
            accum4_kernel<<<NPART * ACC_SPLIT, 1024, 0, stream>>>(
                bins, pbase, (const float4*)X, partial);
            reduce4_kernel<<<NPART, 1024, 0, stream>>>(partial, out);
        } else {
            accum_kernel<<<NPART, 1024, 0, stream>>>(bins, pbase,
                                                     (const float4*)X, out);
        }
    } else {
        // fallback: per-XCD replica atomic path (needs ~10 MB)
        unsigned long long* rep = (unsigned long long*)d_ws;
        const size_t rep_bytes = (size_t)NXCD * N_PIXK * 2 * sizeof(unsigned long long);
        float* X = (float*)((char*)d_ws + rep_bytes);
        const int nrep = NXCD * N_PIXK * 2;
        zero_u64_kernel<<<(nrep + 255) / 256, 256, 0, stream>>>(rep, nrep);
        filt_kernel<<<NB * N_ANG, 256, 0, stream>>>(sin_fan, cosv, filt, X);
        scatter_kernel<<<4096, 256, 0, stream>>>(A_vals, A_rows, A_cols,
                                                 (const float4*)X, rep);
        reduce_clip_kernel<<<(N_PIXK + 255) / 256, 256, 0, stream>>>(rep, out);
    }
}

// Round 8
// 125.902 us; speedup vs baseline: 12.9555x; 1.0180x over previous
//
#include <hip/hip_runtime.h>
#include <stdint.h>

#define N_ANG    360
#define N_DET    357
#define FILT_LEN 713
#define N_COLS   (N_ANG * N_DET)      // 128520 < 2^17
#define N_PIXK   65536
#define NNZK     8388608
#define NB       4

#define NPART    256
#define PART_SH  8                    // partition = row >> 8
#define PART_PIX 256                  // pixels per partition
#define CHUNK    8192                 // nnz per chunk/block in passes 1-2
#define NCHUNK   (NNZK / CHUNK)       // 1024, exact
#define P1_T     256
#define P2_T     1024
#define P2_PER_T (CHUNK / P2_T)       // 8

#define ACC_SPLIT 8                   // sub-blocks per partition in accum

#define FPS      67108864.0f          // 2^26 fixed-point scale
#define FPS_INV  (1.0f / 67108864.0f)

// ---------------------------------------------------------------------------
// Stage 1: r = sin_fan * cos, SAME conv len-713 along detector axis.
// Filter covers whole row: F[b,a,d] = sum_j r[j] * filt[356 + j - d].
// X written [col][b] so accum gathers one float4 per nnz.
// ---------------------------------------------------------------------------
__global__ void filt_kernel(const float* __restrict__ sin_fan,
                            const float* __restrict__ cosv,
                            const float* __restrict__ filt,
                            float* __restrict__ X) {
    __shared__ float s_r[N_DET];
    __shared__ float s_f[FILT_LEN];
    const int blk = blockIdx.x;            // b*N_ANG + a
    const int b   = blk / N_ANG;
    const int a   = blk % N_ANG;
    const int tid = threadIdx.x;

    for (int i = tid; i < N_DET; i += blockDim.x)
        s_r[i] = sin_fan[(size_t)(b * N_ANG + a) * N_DET + i] * cosv[a * N_DET + i];
    for (int i = tid; i < FILT_LEN; i += blockDim.x)
        s_f[i] = filt[i];
    __syncthreads();

    for (int d = tid; d < N_DET; d += blockDim.x) {
        float acc = 0.f;
        const float* fp = &s_f[356 - d];
        #pragma unroll 7
        for (int j = 0; j < N_DET; ++j)
            acc = fmaf(s_r[j], fp[j], acc);
        X[(size_t)(a * N_DET + d) * NB + b] = acc;
    }
}

// ---------------------------------------------------------------------------
// Pass 1: per-chunk partition histogram (native ds_add_u32), int4 loads.
// counts layout: [chunk][part].
// ---------------------------------------------------------------------------
__global__ void hist_kernel(const int* __restrict__ A_rows,
                            unsigned* __restrict__ counts) {
    __shared__ unsigned h[NPART];
    const int chunk = blockIdx.x, tid = threadIdx.x;   // 256
    h[tid] = 0;
    __syncthreads();
    const int4* r4 = (const int4*)(A_rows + chunk * CHUNK);
    #pragma unroll
    for (int k = 0; k < 8; ++k) {                      // 8 int4 = 32 rows/thread
        const int4 rv = r4[tid * 8 + k];
        atomicAdd(&h[rv.x >> PART_SH], 1u);
        atomicAdd(&h[rv.y >> PART_SH], 1u);
        atomicAdd(&h[rv.z >> PART_SH], 1u);
        atomicAdd(&h[rv.w >> PART_SH], 1u);
    }
    __syncthreads();
    counts[chunk * NPART + tid] = h[tid];
}

// ---------------------------------------------------------------------------
// Pass 1.5a: per-partition exclusive prefix over the 1024 chunks.
// ---------------------------------------------------------------------------
__global__ void scanA_kernel(unsigned* __restrict__ counts,
                             unsigned* __restrict__ ptot) {
    const int p = blockIdx.x, tid = threadIdx.x;   // 256 threads
    unsigned v[4], s = 0;
    #pragma unroll
    for (int k = 0; k < 4; ++k) {
        v[k] = counts[(size_t)(tid * 4 + k) * NPART + p];
        s += v[k];
    }
    __shared__ unsigned sc[256];
    sc[tid] = s;
    __syncthreads();
    for (int off = 1; off < 256; off <<= 1) {
        unsigned t = (tid >= off) ? sc[tid - off] : 0u;
        __syncthreads();
        sc[tid] += t;
        __syncthreads();
    }
    unsigned run = sc[tid] - s;                    // exclusive
    if (tid == 255) ptot[p] = sc[255];
    #pragma unroll
    for (int k = 0; k < 4; ++k) {
        counts[(size_t)(tid * 4 + k) * NPART + p] = run;
        run += v[k];
    }
}

// ---------------------------------------------------------------------------
// Pass 1.5b: exclusive scan of the 256 partition totals -> part_base[257].
// ---------------------------------------------------------------------------
__global__ void scanB_kernel(const unsigned* __restrict__ ptot,
                             unsigned* __restrict__ part_base) {
    const int tid = threadIdx.x;                   // 256
    unsigned s = ptot[tid];
    __shared__ unsigned sc[256];
    sc[tid] = s;
    __syncthreads();
    for (int off = 1; off < 256; off <<= 1) {
        unsigned t = (tid >= off) ? sc[tid - off] : 0u;
        __syncthreads();
        sc[tid] += t;
        __syncthreads();
    }
    part_base[tid] = sc[tid] - s;
    if (tid == 255) part_base[256] = sc[255];
}

// ---------------------------------------------------------------------------
// Pass 2: reorder each chunk by partition in LDS, write packed 8B entries
// (val f32, row_local<<17 | col) as contiguous per-partition runs.
// 1024 threads, 76.8KB LDS -> 2 blocks/CU. Thread owns 8 CONSECUTIVE
// entries so rows/vals/cols load as int4/float4 (order within a chunk is
// irrelevant: ranks are atomically allocated, grouping is preserved).
// ---------------------------------------------------------------------------
__global__ void __launch_bounds__(1024)
bin_kernel(const float* __restrict__ A_vals,
           const int*   __restrict__ A_rows,
           const int*   __restrict__ A_cols,
           const unsigned* __restrict__ offsets,
           const unsigned* __restrict__ part_base,
           uint2* __restrict__ bins) {
    __shared__ uint2 stage[CHUNK];            // 64 KB
    __shared__ unsigned char spart[CHUNK];    // 8 KB
    __shared__ unsigned loff[NPART], cnt[NPART], goff[NPART];
    const int chunk = blockIdx.x, tid = threadIdx.x;   // 1024
    if (tid < NPART) cnt[tid] = 0;
    if (tid >= NPART && tid < 2 * NPART) loff[tid - NPART] = 0;
    __syncthreads();

    const int base = chunk * CHUNK;
    const int4*   r4 = (const int4*)(A_rows + base);
    const int4*   c4 = (const int4*)(A_cols + base);
    const float4* v4 = (const float4*)(A_vals + base);
    int rows[P2_PER_T];
    {
        const int4 ra = r4[tid * 2], rb = r4[tid * 2 + 1];
        rows[0] = ra.x; rows[1] = ra.y; rows[2] = ra.z; rows[3] = ra.w;
        rows[4] = rb.x; rows[5] = rb.y; rows[6] = rb.z; rows[7] = rb.w;
    }
    #pragma unroll
    for (int k = 0; k < P2_PER_T; ++k)
        atomicAdd(&loff[rows[k] >> PART_SH], 1u);      // histogram into loff
    __syncthreads();

    // exclusive scan loff in place (Hillis-Steele over first 256 threads)
    unsigned hv = 0;
    if (tid < NPART) hv = loff[tid];
    for (int off = 1; off < NPART; off <<= 1) {
        unsigned t = 0;
        if (tid < NPART && tid >= off) t = loff[tid - off];
        __syncthreads();
        if (tid < NPART) loff[tid] += t;
        __syncthreads();
    }
    if (tid < NPART) {
        loff[tid] -= hv;                               // inclusive -> exclusive
        goff[tid] = part_base[tid] + offsets[chunk * NPART + tid];
    }
    __syncthreads();

    {
        const int4   ca = c4[tid * 2], cb = c4[tid * 2 + 1];
        const float4 va = v4[tid * 2], vb = v4[tid * 2 + 1];
        const unsigned cols[P2_PER_T] = {
            (unsigned)ca.x, (unsigned)ca.y, (unsigned)ca.z, (unsigned)ca.w,
            (unsigned)cb.x, (unsigned)cb.y, (unsigned)cb.z, (unsigned)cb.w };
        const float vals[P2_PER_T] = { va.x, va.y, va.z, va.w,
                                       vb.x, vb.y, vb.z, vb.w };
        #pragma unroll
        for (int k = 0; k < P2_PER_T; ++k) {
            const int row = rows[k];
            const int p = row >> PART_SH;
            const unsigned rank = atomicAdd(&cnt[p], 1u);
            const unsigned pos = loff[p] + rank;
            stage[pos] = make_uint2(__float_as_uint(vals[k]),
                                    ((unsigned)(row & (PART_PIX - 1)) << 17) | cols[k]);
            spart[pos] = (unsigned char)p;
        }
    }
    __syncthreads();

    #pragma unroll
    for (int k = 0; k < P2_PER_T; ++k) {
        const int i = k * P2_T + tid;
        const unsigned p = spart[i];
        const unsigned glob = goff[p] + (unsigned)i - loff[p];
        bins[glob] = stage[i];
    }
}

// ---------------------------------------------------------------------------
// Pass 3 (split 8): each sub-block accumulates its eighth of a partition's
// bin range into LDS u64 accumulators: 2 fixed-point (2^26) channels packed
// per u64, added with NATIVE ds_add_u64 — HALF the LDS-atomic instructions
// of the 4x u32 version (the hypothesized accum serializer). Low half exact
// mod 2^32; carries pollute the high channel by 1 LSB (2^-26) per negative
// low term (~2e-7/partial) — noise vs 6.3e-4 threshold. Partials exact u64.
// ---------------------------------------------------------------------------
__global__ void __launch_bounds__(1024)
accum8_kernel(const uint2* __restrict__ bins,
              const unsigned* __restrict__ part_base,
              const float4* __restrict__ X4,
              unsigned long long* __restrict__ partial) {
    __shared__ unsigned long long iacc[2 * PART_PIX];   // 4 KB
    const int bp = blockIdx.x;
    const int p = bp >> 3, j = bp & 7;
    const int tid = threadIdx.x;
    if (tid < 2 * PART_PIX) iacc[tid] = 0ULL;
    __syncthreads();

    const unsigned s = part_base[p], e = part_base[p + 1];
    const unsigned len = e - s;
    const unsigned q = (len + ACC_SPLIT - 1) / ACC_SPLIT;
    const unsigned qs = s + j * q;
    const unsigned qe = min(qs + q, e);

    #pragma unroll 4
    for (unsigned i = qs + tid; i < qe; i += 1024) {
        const uint2 en = bins[i];
        const float v = __uint_as_float(en.x);
        const unsigned col = en.y & 0x1FFFFu;
        const unsigned rl  = en.y >> 17;
        const float4 x = X4[col];
        const int i0 = __float2int_rn(v * x.x * FPS);
        const int i1 = __float2int_rn(v * x.y * FPS);
        const int i2 = __float2int_rn(v * x.z * FPS);
        const int i3 = __float2int_rn(v * x.w * FPS);
        const unsigned long long w0 =
            ((unsigned long long)(unsigned)i1 << 32) + (unsigned long long)(unsigned)i0;
        const unsigned long long w1 =
            ((unsigned long long)(unsigned)i3 << 32) + (unsigned long long)(unsigned)i2;
        atomicAdd(&iacc[rl], w0);
        atomicAdd(&iacc[PART_PIX + rl], w1);
    }
    __syncthreads();

    if (tid < 2 * PART_PIX)
        partial[((size_t)j * NPART + p) * (2 * PART_PIX) + tid] = iacc[tid];
}

// ---------------------------------------------------------------------------
// Pass 3b: sum the 8 u64 partials, decode both packed channels, clip, write.
// ---------------------------------------------------------------------------
__global__ void reduce8_kernel(const unsigned long long* __restrict__ partial,
                               float* __restrict__ out) {
    const int g = blockIdx.x * blockDim.x + threadIdx.x;  // 0 .. 256*512-1
    const int p = g >> 9, t = g & 511;
    const int pair = t >> 8, rl = t & (PART_PIX - 1);
    unsigned long long s = 0;
    #pragma unroll
    for (int j = 0; j < ACC_SPLIT; ++j)
        s += partial[((size_t)j * NPART + p) * (2 * PART_PIX) + t];
    const float clo = (float)(int)(unsigned)(s & 0xffffffffULL) * FPS_INV;
    const float chi = (float)(int)(unsigned)(s >> 32)           * FPS_INV;
    const int ch0 = pair * 2, ch1 = pair * 2 + 1;
    out[(size_t)ch0 * N_PIXK + p * PART_PIX + rl] = fminf(fmaxf(clo, 0.f), 1.f);
    out[(size_t)ch1 * N_PIXK + p * PART_PIX + rl] = fminf(fmaxf(chi, 0.f), 1.f);
}

// ---------------------------------------------------------------------------
// Pass 3 (single-kernel fallback when ws lacks room for partials).
// ---------------------------------------------------------------------------
__global__ void __launch_bounds__(1024)
accum_kernel(const uint2* __restrict__ bins,
             const unsigned* __restrict__ part_base,
             const float4* __restrict__ X4,
             float* __restrict__ out) {
    __shared__ unsigned iacc[NB][PART_PIX];
    const int p = blockIdx.x, tid = threadIdx.x;
    ((unsigned*)iacc)[tid] = 0u;
    __syncthreads();

    const unsigned s = part_base[p], e = part_base[p + 1];
    #pragma unroll 4
    for (unsigned i = s + tid; i < e; i += 1024) {
        const uint2 en = bins[i];
        const float v = __uint_as_float(en.x);
        const unsigned col = en.y & 0x1FFFFu;
        const unsigned rl  = en.y >> 17;
        const float4 x = X4[col];
        atomicAdd(&iacc[0][rl], (unsigned)__float2int_rn(v * x.x * FPS));
        atomicAdd(&iacc[1][rl], (unsigned)__float2int_rn(v * x.y * FPS));
        atomicAdd(&iacc[2][rl], (unsigned)__float2int_rn(v * x.z * FPS));
        atomicAdd(&iacc[3][rl], (unsigned)__float2int_rn(v * x.w * FPS));
    }
    __syncthreads();

    const int ch = tid >> 8, rl = tid & (PART_PIX - 1);
    const float r = (float)(int)iacc[ch][rl] * FPS_INV;
    out[(size_t)ch * N_PIXK + p * PART_PIX + rl] = fminf(fmaxf(r, 0.f), 1.f);
}

// ------------------------- fallback (round-3 path) -------------------------
#define NXCD 8
#define FP_SCALE 16777216.0f
#define FP_INV   (1.0 / 16777216.0)
__global__ void zero_u64_kernel(unsigned long long* __restrict__ p, int n) {
    int i = blockIdx.x * blockDim.x + threadIdx.x;
    if (i < n) p[i] = 0ULL;
}
__device__ __forceinline__ unsigned get_xcc_id() {
    unsigned x;
    asm volatile("s_getreg_b32 %0, hwreg(HW_REG_XCC_ID, 0, 4)" : "=s"(x));
    return x & (NXCD - 1);
}
__global__ void scatter_kernel(const float*  __restrict__ A_vals,
                               const int*    __restrict__ A_rows,
                               const int*    __restrict__ A_cols,
                               const float4* __restrict__ X4,
                               unsigned long long* __restrict__ rep) {
    unsigned long long* myrep = rep + (size_t)get_xcc_id() * N_PIXK * 2;
    const int stride = gridDim.x * blockDim.x;
    for (int i = blockIdx.x * blockDim.x + threadIdx.x; i < NNZK; i += stride) {
        const float v = A_vals[i];
        const float4 x = X4[A_cols[i]];
        const int r = A_rows[i];
        const int i0 = __float2int_rn(v * x.x * FP_SCALE);
        const int i1 = __float2int_rn(v * x.y * FP_SCALE);
        const int i2 = __float2int_rn(v * x.z * FP_SCALE);
        const int i3 = __float2int_rn(v * x.w * FP_SCALE);
        const unsigned long long w0 =
            ((unsigned long long)(unsigned)i1 << 32) + (unsigned long long)(unsigned)i0;
        const unsigned long long w1 =
            ((unsigned long long)(unsigned)i3 << 32) + (unsigned long long)(unsigned)i2;
        __hip_atomic_fetch_add(&myrep[(size_t)r * 2 + 0], w0,
                               __ATOMIC_RELAXED, __HIP_MEMORY_SCOPE_WORKGROUP);
        __hip_atomic_fetch_add(&myrep[(size_t)r * 2 + 1], w1,
                               __ATOMIC_RELAXED, __HIP_MEMORY_SCOPE_WORKGROUP);
    }
}
__global__ void reduce_clip_kernel(const unsigned long long* __restrict__ rep,
                                   float* __restrict__ out) {
    const int p = blockIdx.x * blockDim.x + threadIdx.x;
    if (p >= N_PIXK) return;
    unsigned long long s0 = 0, s1 = 0;
    #pragma unroll
    for (int x = 0; x < NXCD; ++x) {
        s0 += rep[((size_t)x * N_PIXK + p) * 2 + 0];
        s1 += rep[((size_t)x * N_PIXK + p) * 2 + 1];
    }
    const float c0 = (float)((double)(int)(unsigned)(s0 & 0xffffffffULL) * FP_INV);
    const float c1 = (float)((double)(int)(unsigned)(s0 >> 32)           * FP_INV);
    const float c2 = (float)((double)(int)(unsigned)(s1 & 0xffffffffULL) * FP_INV);
    const float c3 = (float)((double)(int)(unsigned)(s1 >> 32)           * FP_INV);
    out[0 * N_PIXK + p] = fminf(fmaxf(c0, 0.f), 1.f);
    out[1 * N_PIXK + p] = fminf(fmaxf(c1, 0.f), 1.f);
    out[2 * N_PIXK + p] = fminf(fmaxf(c2, 0.f), 1.f);
    out[3 * N_PIXK + p] = fminf(fmaxf(c3, 0.f), 1.f);
}

extern "C" void kernel_launch(void* const* d_in, const int* in_sizes, int n_in,
                              void* d_out, int out_size, void* d_ws, size_t ws_size,
                              hipStream_t stream) {
    const float* sin_fan = (const float*)d_in[0];
    const float* cosv    = (const float*)d_in[1];
    const float* filt    = (const float*)d_in[2];
    const float* A_vals  = (const float*)d_in[3];
    const int*   A_rows  = (const int*)d_in[4];
    const int*   A_cols  = (const int*)d_in[5];
    float* out = (float*)d_out;

    // ws layout for sort path:
    //   [0, 2MB)            X          (N_COLS*4 floats = 2,056,320 B)
    //   [2MB, 3MB)          counts     (NCHUNK*NPART u32 = 1 MB)
    //   [3MB, +2KB)         part_base  (257 u32)
    //   [3MB+2KB, +2KB)     ptot       (256 u32)
    //   [3MB+4KB, +64MB)    bins       (NNZK uint2 = 64 MB)
    //   [.., +8MB)          partial    (8 * 256 * 512 u64 = 8 MB) [optional]
    const size_t MB = 1024 * 1024;
    const size_t need_sort  = 3 * MB + 4096 + (size_t)NNZK * sizeof(uint2);
    const size_t need_split = need_sort +
        (size_t)ACC_SPLIT * NPART * (2 * PART_PIX) * sizeof(unsigned long long);

    if (ws_size >= need_sort) {
        float*    X      = (float*)d_ws;
        unsigned* counts = (unsigned*)((char*)d_ws + 2 * MB);
        unsigned* pbase  = (unsigned*)((char*)d_ws + 3 * MB);
        unsigned* ptot   = (unsigned*)((char*)d_ws + 3 * MB + 2048);
        uint2*    bins   = (uint2*)((char*)d_ws + 3 * MB + 4096);
        unsigned long long* partial =
            (unsigned long long*)((char*)d_ws + need_sort);

        filt_kernel<<<NB * N_ANG, 256, 0, stream>>>(sin_fan, cosv, filt, X);
        hist_kernel<<<NCHUNK, P1_T, 0, stream>>>(A_rows, counts);
        scanA_kernel<<<NPART, 256, 0, stream>>>(counts, ptot);
        scanB_kernel<<<1, 256, 0, stream>>>(ptot, pbase);
        bin_kernel<<<NCHUNK, P2_T, 0, stream>>>(A_vals, A_rows, A_cols, counts,
                                                pbase, bins);
        if (ws_size >= need_split) {
            accum8_kernel<<<NPART * ACC_SPLIT, 1024, 0, stream>>>(
                bins, pbase, (const float4*)X, partial);
            reduce8_kernel<<<(NPART * 2 * PART_PIX) / 1024, 1024, 0, stream>>>(
                partial, out);
        } else {
            accum_kernel<<<NPART, 1024, 0, stream>>>(bins, pbase,
                                                     (const float4*)X, out);
        }
    } else {
        // fallback: per-XCD replica atomic path (needs ~10 MB)
        unsigned long long* rep = (unsigned long long*)d_ws;
        const size_t rep_bytes = (size_t)NXCD * N_PIXK * 2 * sizeof(unsigned long long);
        float* X = (float*)((char*)d_ws + rep_bytes);
        const int nrep = NXCD * N_PIXK * 2;
        zero_u64_kernel<<<(nrep + 255) / 256, 256, 0, stream>>>(rep, nrep);
        filt_kernel<<<NB * N_ANG, 256, 0, stream>>>(sin_fan, cosv, filt, X);
        scatter_kernel<<<4096, 256, 0, stream>>>(A_vals, A_rows, A_cols,
                                                 (const float4*)X, rep);
        reduce_clip_kernel<<<(N_PIXK + 255) / 256, 256, 0, stream>>>(rep, out);
    }
}